// Round 2
// baseline (772.526 us; speedup 1.0000x reference)
//
#include <hip/hip_runtime.h>
#include <hip/hip_bf16.h>

typedef __hip_bfloat16 bf16;

constexpr int CB = 8;     // batch
constexpr int CT = 512;   // T
constexpr int CN = 64;    // N
constexpr int CD = 128;   // D
constexpr int CP = 96;    // PRED
constexpr int CH = 8;     // HEADS
constexpr int CDH = 16;   // head dim
constexpr int CHID = 256; // HID
constexpr int CM = 32;    // CEM freq tokens
constexpr int CG = 64;    // TEM freq tokens
constexpr float TWO_PI = 6.28318530717958647692f;

__device__ __forceinline__ float b2f(const bf16 v) { return __bfloat162float(v); }

// dtype-agnostic load: f==true -> input is float32, else bf16
__device__ __forceinline__ float LD(const void* p, int i, bool f) {
  return f ? ((const float*)p)[i] : __bfloat162float(((const bf16*)p)[i]);
}

// ---------------- K_detect: decide fp32 vs bf16 from x's bit patterns --------------
// bf16 N(0,1) data: every 16-bit half has a sane exponent. fp32 data: low halves are
// mantissa bits (uniform) -> ~80% have absurd bf16 exponents.
__global__ void k_detect(const unsigned int* xw, float* flag) {
  __shared__ int cnt;
  if (threadIdx.x == 0) cnt = 0;
  __syncthreads();
  int c = 0;
  for (int i = threadIdx.x; i < 2048; i += 256) {
    unsigned int w = xw[i];
    unsigned int e = (w >> 7) & 0xFF; // exponent field of LOW 16-bit half as bf16
    if (e >= 0x90 || e <= 0x60) c++;
  }
  atomicAdd(&cnt, c);
  __syncthreads();
  if (threadIdx.x == 0) flag[0] = (cnt > 100) ? 1.f : 0.f;
}

// ---------------- K0: tiny precomputations (rank-1 CEM folding, TEM folded weights) --------------
__global__ void k0_precomp(const void* emb, const void* cWq, const void* cWk, const void* cWv,
                           const void* cWo, const void* tWq, const void* tWk, const void* tWv,
                           const void* tWo, const void* drw, const float* gflag,
                           float* g_ch, float* g_ewo, float* g_ewq, float* g_ewk, float* g_ewv,
                           float* g_wod) {
  bool f32 = gflag[0] != 0.f;
  __shared__ float eml[CD], eql[CD], ekl[CD], evl[CD], ewol[CH][CD];
  int tid = threadIdx.x; // 128
  eml[tid] = LD(emb, tid, f32);
  __syncthreads();
  {
    int e = tid;
    float aq = 0, ak = 0, av = 0;
    for (int d = 0; d < CD; ++d) {
      float em = eml[d];
      aq += em * LD(cWq, d * CD + e, f32);
      ak += em * LD(cWk, d * CD + e, f32);
      av += em * LD(cWv, d * CD + e, f32);
    }
    eql[e] = aq; ekl[e] = ak; evl[e] = av;
  }
  __syncthreads();
  if (tid < CH) {
    float c = 0;
    for (int j = 0; j < CDH; ++j) c += eql[tid * CDH + j] * ekl[tid * CDH + j];
    g_ch[tid] = fabsf(c);
  }
  {
    int e = tid;
    for (int h = 0; h < CH; ++h) {
      float a = 0;
      for (int j = 0; j < CDH; ++j) a += evl[h * CDH + j] * LD(cWo, (h * CDH + j) * CD + e, f32);
      ewol[h][e] = a; g_ewo[h * CD + e] = a;
    }
  }
  __syncthreads();
  {
    int e = tid;
    for (int h = 0; h < CH; ++h) {
      float aq = 0, ak = 0, av = 0;
      for (int d = 0; d < CD; ++d) {
        float w = ewol[h][d];
        aq += w * LD(tWq, d * CD + e, f32);
        ak += w * LD(tWk, d * CD + e, f32);
        av += w * LD(tWv, d * CD + e, f32);
      }
      g_ewq[h * CD + e] = aq; g_ewk[h * CD + e] = ak; g_ewv[h * CD + e] = av;
    }
    float a = 0;
    for (int e2 = 0; e2 < CD; ++e2) a += LD(tWo, e * CD + e2, f32) * LD(drw, e2, f32);
    g_wod[e] = a;
  }
}

// ---------------- K_ow: Ow[g,p] = sum_t out_w[t,p] * e^{+2pi i g t/512} --------------
__global__ void k_ow(const void* out_w, const float* gflag, float* owr, float* owi) {
  bool f32 = gflag[0] != 0.f;
  int idx = blockIdx.x * blockDim.x + threadIdx.x;
  if (idx >= CG * CP) return;
  int g = idx / CP, p = idx % CP;
  float sr = 0, si = 0;
  for (int t = 0; t < CT; ++t) {
    int k = (g * t) & (CT - 1);
    float th = (float)k * (TWO_PI / CT);
    float s, c;
    sincosf(th, &s, &c);
    float w = LD(out_w, t * CP + p, f32);
    sr += w * c; si += w * s;
  }
  owr[idx] = sr; owi[idx] = si;
}

// ---------------- K1: decomposition (moving averages + 2-way softmax) --------------
__global__ void k1_decomp(const void* x, const void* dec_w, const void* dec_b, const float* gflag,
                          float* res, float* trend) {
  bool f32 = gflag[0] != 0.f;
  __shared__ float xl[CT];
  int blk = blockIdx.x;
  int b = blk >> 6, n = blk & 63;
  int tid = threadIdx.x; // 256
  size_t base = (size_t)b * CT * CN + n;
  xl[tid] = LD(x, base + (size_t)tid * CN, f32);
  xl[tid + 256] = LD(x, base + (size_t)(tid + 256) * CN, f32);
  __syncthreads();
  float w0 = LD(dec_w, 0, f32), w1 = LD(dec_w, 1, f32);
  float c0 = LD(dec_b, 0, f32), c1 = LD(dec_b, 1, f32);
  for (int t = tid; t < CT; t += 256) {
    float s17 = 0;
    for (int j = -8; j <= 8; ++j) {
      int u = t + j; u = u < 0 ? 0 : (u > CT - 1 ? CT - 1 : u);
      s17 += xl[u];
    }
    float s49 = 0;
    for (int j = -24; j <= 24; ++j) {
      int u = t + j; u = u < 0 ? 0 : (u > CT - 1 ? CT - 1 : u);
      s49 += xl[u];
    }
    float m0 = s17 * (1.f / 17.f), m1 = s49 * (1.f / 49.f);
    float xv = xl[t];
    float l0 = xv * w0 + c0, l1 = xv * w1 + c1;
    float mx = fmaxf(l0, l1);
    float e0 = __expf(l0 - mx), e1 = __expf(l1 - mx);
    float tr = (e0 * m0 + e1 * m1) / (e0 + e1);
    size_t o = ((size_t)(b * CT + t)) * CN + n;
    trend[o] = tr;
    res[o] = xv - tr;
  }
}

// ---------------- K2: trend MLP (512 -> 256 -> 256 -> 96 per (b,n) row) --------------
__global__ void k2_mlp(const float* trend, const void* w1, const void* bb1, const void* w2,
                       const void* bb2, const void* w3, const void* bb3, const float* gflag,
                       float* trendo) {
  bool f32 = gflag[0] != 0.f;
  __shared__ float rowl[CT], h1l[CHID], h2l[CHID];
  int blk = blockIdx.x;
  int b = blk >> 6, n = blk & 63;
  int tid = threadIdx.x; // 256
  const float* tb = trend + (size_t)b * CT * CN + n;
  rowl[tid] = tb[(size_t)tid * CN];
  rowl[tid + 256] = tb[(size_t)(tid + 256) * CN];
  __syncthreads();
  {
    float a = LD(bb1, tid, f32);
    for (int t = 0; t < CT; ++t) a += rowl[t] * LD(w1, t * CHID + tid, f32);
    h1l[tid] = fmaxf(a, 0.f);
  }
  __syncthreads();
  {
    float a = LD(bb2, tid, f32);
    for (int i = 0; i < CHID; ++i) a += h1l[i] * LD(w2, i * CHID + tid, f32);
    h2l[tid] = fmaxf(a, 0.f);
  }
  __syncthreads();
  if (tid < CP) {
    float a = LD(bb3, tid, f32);
    for (int i = 0; i < CHID; ++i) a += h2l[i] * LD(w3, i * CP + tid, f32);
    trendo[((size_t)(b * CN + n)) * CP + tid] = a;
  }
}

// ---------------- K3: CEM collapsed attention -> P[b,t,h,n] --------------
__global__ __launch_bounds__(64) void k3_cem(const float* res, const float* g_ch, float* P) {
  __shared__ float rowl[CN], twc[CN], tws[CN];
  __shared__ float Rr[CM], Ri[CM], aR[CM];
  __shared__ float Sr[CH * CM], Si[CH * CM], chl[CH];
  int blk = blockIdx.x;
  int b = blk >> 9, t = blk & 511;
  int tid = threadIdx.x; // 64
  rowl[tid] = res[((size_t)(b * CT + t)) * CN + tid];
  twc[tid] = cosf((float)tid * (TWO_PI / CN));
  tws[tid] = sinf((float)tid * (TWO_PI / CN));
  if (tid < CH) chl[tid] = g_ch[tid];
  __syncthreads();
  if (tid < CM) {
    float rr = 0, ri = 0;
    int idx = 0;
    for (int n2 = 0; n2 < CN; ++n2) {
      rr += rowl[n2] * twc[idx];
      ri -= rowl[n2] * tws[idx];
      idx = (idx + tid) & (CN - 1);
    }
    Rr[tid] = rr; Ri[tid] = ri; aR[tid] = sqrtf(rr * rr + ri * ri);
  }
  __syncthreads();
  float amax = 0;
  for (int m = 0; m < CM; ++m) amax = fmaxf(amax, aR[m]);
  for (int i = 0; i < 4; ++i) {
    int pair = tid + 64 * i;
    int h = pair >> 5, m = pair & 31;
    float alpha = 0.25f * chl[h] * aR[m];
    float den = 0, sr = 0, si = 0;
    for (int n2 = 0; n2 < CM; ++n2) {
      float e = __expf(alpha * (aR[n2] - amax));
      den += e; sr += e * Rr[n2]; si += e * Ri[n2];
    }
    Sr[pair] = sr / den; Si[pair] = si / den;
  }
  __syncthreads();
  float* Pb = P + ((size_t)(b * CT + t)) * CH * CN;
  int n2 = tid;
  for (int h = 0; h < CH; ++h) {
    float a = Sr[h * CM]; // f = 0 term (Re only; imag dropped per irfft semantics)
    int idx = n2 & (CN - 1);
    for (int f = 1; f < CM; ++f) {
      a += 2.f * (Sr[h * CM + f] * twc[idx] - Si[h * CM + f] * tws[idx]);
      idx = (idx + n2) & (CN - 1);
    }
    Pb[h * CN + n2] = a * (1.f / CN);
  }
}

// ---------------- K4: Q[b,n,g,h] = sum_t P[b,t,h,n] e^{-2pi i g t / 512} --------------
__global__ __launch_bounds__(256) void k4_qdft(const float* P, float* Q) {
  __shared__ float Pl[CT][CH];
  __shared__ float twc[CT], tws[CT];
  int blk = blockIdx.x;
  int b = blk >> 6, n = blk & 63;
  int tid = threadIdx.x; // 256
  for (int i = tid; i < CT * CH; i += 256) {
    int t = i >> 3, h = i & 7;
    Pl[t][h] = P[(((size_t)(b * CT + t)) * CH + h) * CN + n];
  }
  for (int i = tid; i < CT; i += 256) {
    twc[i] = cosf((float)i * (TWO_PI / CT));
    tws[i] = sinf((float)i * (TWO_PI / CT));
  }
  __syncthreads();
  int g1 = tid >> 3, h = tid & 7, g2 = g1 + 32;
  float r1 = 0, i1 = 0, r2 = 0, i2 = 0;
  int idx1 = 0, idx2 = 0;
  for (int t = 0; t < CT; ++t) {
    float p = Pl[t][h];
    r1 += p * twc[idx1]; i1 -= p * tws[idx1];
    r2 += p * twc[idx2]; i2 -= p * tws[idx2];
    idx1 = (idx1 + g1) & (CT - 1);
    idx2 = (idx2 + g2) & (CT - 1);
  }
  float* Qb = Q + ((size_t)(b * CN + n)) * CG * CH * 2;
  Qb[(g1 * CH + h) * 2] = r1; Qb[(g1 * CH + h) * 2 + 1] = i1;
  Qb[(g2 * CH + h) * 2] = r2; Qb[(g2 * CH + h) * 2 + 1] = i2;
}

// ---------------- K5: TEM complex attention per (b, n, head) -> Zp[b,n,h,g] --------------
__global__ __launch_bounds__(256) void k5_tem(const float* Q, const float* g_ewq,
                                              const float* g_ewk, const float* g_ewv,
                                              const float* g_wod, float* Zp) {
  __shared__ float Qr[CG][CH], Qi[CG][CH];
  __shared__ float eq[CH][CDH], ek[CH][CDH], ev[CH][CDH], wd[CDH];
  __shared__ float qr[CG][CDH + 1], qi[CG][CDH + 1];
  __shared__ float kr[CG][CDH + 1], ki[CG][CDH + 1];
  __shared__ float vr[CG][CDH + 1], vi[CG][CDH + 1];
  __shared__ float sA[CG][CG + 1];
  __shared__ float rinv[CG];
  int blk = blockIdx.x;
  int h = blk & 7, n = (blk >> 3) & 63, b = blk >> 9;
  int tid = threadIdx.x; // 256
  const float* Qb = Q + ((size_t)(b * CN + n)) * CG * CH * 2;
  for (int i = tid; i < CG * CH * 2; i += 256) {
    int g = i >> 4, r = (i >> 1) & 7, c = i & 1;
    float v = Qb[i];
    if (c == 0) Qr[g][r] = v; else Qi[g][r] = v;
  }
  if (tid < CH * CDH) {
    int hh = tid >> 4, j = tid & 15;
    eq[hh][j] = g_ewq[hh * CD + h * CDH + j];
    ek[hh][j] = g_ewk[hh * CD + h * CDH + j];
    ev[hh][j] = g_ewv[hh * CD + h * CDH + j];
  }
  if (tid < CDH) wd[tid] = g_wod[h * CDH + tid];
  __syncthreads();
  // qkv for this head: rank-8 expansion from Q
  for (int i = tid; i < CG * CDH; i += 256) {
    int g = i >> 4, j = i & 15;
    float aqr = 0, aqi = 0, akr = 0, aki = 0, avr = 0, avi = 0;
    for (int hh = 0; hh < CH; ++hh) {
      float xr = Qr[g][hh], xi = Qi[g][hh];
      float wq = eq[hh][j], wk = ek[hh][j], wv = ev[hh][j];
      aqr += xr * wq; aqi += xi * wq;
      akr += xr * wk; aki += xi * wk;
      avr += xr * wv; avi += xi * wv;
    }
    qr[g][j] = aqr; qi[g][j] = aqi;
    kr[g][j] = akr; ki[g][j] = aki;
    vr[g][j] = avr; vi[g][j] = avi;
  }
  __syncthreads();
  // scores |q . conj(k)| / 4
  for (int i = tid; i < CG * CG; i += 256) {
    int m = i >> 6, g = i & 63;
    float sr = 0, si = 0;
    for (int j = 0; j < CDH; ++j) {
      float a = qr[m][j], bq = qi[m][j], c = kr[g][j], d2 = ki[g][j];
      sr += a * c + bq * d2;
      si += bq * c - a * d2;
    }
    sA[m][g] = 0.25f * sqrtf(sr * sr + si * si);
  }
  __syncthreads();
  if (tid < CG) {
    int m = tid;
    float mx = -1e30f;
    for (int g = 0; g < CG; ++g) mx = fmaxf(mx, sA[m][g]);
    float s = 0;
    for (int g = 0; g < CG; ++g) {
      float e = __expf(sA[m][g] - mx);
      sA[m][g] = e; s += e;
    }
    rinv[m] = 1.f / s;
  }
  __syncthreads();
  // o = softmax(w) @ v  (reuse qr/qi as o storage)
  for (int i = tid; i < CG * CDH; i += 256) {
    int m = i >> 4, j = i & 15;
    float orr = 0, oii = 0;
    for (int g = 0; g < CG; ++g) {
      float w = sA[m][g];
      orr += w * vr[g][j];
      oii += w * vi[g][j];
    }
    float rv = rinv[m];
    qr[m][j] = orr * rv; qi[m][j] = oii * rv;
  }
  __syncthreads();
  if (tid < CG) {
    int g = tid;
    float zr = 0, zi = 0;
    for (int j = 0; j < CDH; ++j) {
      zr += qr[g][j] * wd[j];
      zi += qi[g][j] * wd[j];
    }
    size_t o = (((size_t)((b * CN + n) * CH) + h) * CG + g) * 2;
    Zp[o] = zr; Zp[o + 1] = zi;
  }
}

// ---------------- K6: reduce Z over heads, apply Ow transform + fuse with trend branch ----------
__global__ void k6_final(const float* Zp, const float* owr, const float* owi, const float* trendo,
                         const void* dr_b, const void* out_b, const void* wfuse,
                         const float* gflag, void* out) {
  bool f32 = gflag[0] != 0.f;
  __shared__ float zr[CG], zi[CG];
  int blk = blockIdx.x;
  int b = blk >> 6, n = blk & 63;
  int tid = threadIdx.x; // 128
  {
    int g = tid >> 1, c = tid & 1;
    const float* Zb = Zp + ((size_t)((b * CN + n) * CH)) * CG * 2;
    float a = 0;
    for (int h = 0; h < CH; ++h) a += Zb[(h * CG + g) * 2 + c];
    if (c == 0) zr[g] = a; else zi[g] = a;
  }
  __syncthreads();
  if (tid < CP) {
    int p = tid;
    float acc = zr[0] * owr[p] - zi[0] * owi[p]; // g=0 (owi[0,p]==0 -> bin-0 imag dropped)
    for (int g = 1; g < CG; ++g)
      acc += 2.f * (zr[g] * owr[g * CP + p] - zi[g] * owi[g * CP + p]);
    float xo = acc * (1.f / CT) + LD(dr_b, 0, f32) * owr[p] + LD(out_b, p, f32);
    float val = LD(wfuse, 0, f32) * xo + LD(wfuse, 1, f32) * trendo[((size_t)(b * CN + n)) * CP + p];
    size_t oidx = ((size_t)(b * CP + p)) * CN + n;
    if (f32) ((float*)out)[oidx] = val;
    else ((bf16*)out)[oidx] = __float2bfloat16(val);
  }
}

extern "C" void kernel_launch(void* const* d_in, const int* in_sizes, int n_in,
                              void* d_out, int out_size, void* d_ws, size_t ws_size,
                              hipStream_t stream) {
  const void* x = d_in[0];
  const void* emb = d_in[1];
  const void* dec_w = d_in[2];
  const void* dec_b = d_in[3];
  const void* mlp_w1 = d_in[4];
  const void* mlp_b1 = d_in[5];
  const void* mlp_w2 = d_in[6];
  const void* mlp_b2 = d_in[7];
  const void* mlp_w3 = d_in[8];
  const void* mlp_b3 = d_in[9];
  const void* cWq = d_in[10];
  const void* cWk = d_in[11];
  const void* cWv = d_in[12];
  const void* cWo = d_in[13];
  const void* tWq = d_in[14];
  const void* tWk = d_in[15];
  const void* tWv = d_in[16];
  const void* tWo = d_in[17];
  const void* drw = d_in[18];
  const void* drb = d_in[19];
  const void* out_w = d_in[20];
  const void* out_b = d_in[21];
  const void* wfuse = d_in[22];

  float* W = (float*)d_ws;
  float* res = W;    W += (size_t)CB * CT * CN;
  float* trend = W;  W += (size_t)CB * CT * CN;
  float* trendo = W; W += (size_t)CB * CN * CP;
  float* Pbuf = W;   W += (size_t)CB * CT * CH * CN;
  float* Qbuf = W;   W += (size_t)CB * CN * CG * CH * 2;
  float* Zp = W;     W += (size_t)CB * CN * CH * CG * 2;
  float* ch = W;     W += 8;
  float* ewo = W;    W += CH * CD;
  float* ewq = W;    W += CH * CD;
  float* ewk = W;    W += CH * CD;
  float* ewv = W;    W += CH * CD;
  float* wod = W;    W += CD;
  float* owr = W;    W += CG * CP;
  float* owi = W;    W += CG * CP;
  float* gflag = W;  W += 64;

  k_detect<<<1, 256, 0, stream>>>((const unsigned int*)x, gflag);
  k0_precomp<<<1, 128, 0, stream>>>(emb, cWq, cWk, cWv, cWo, tWq, tWk, tWv, tWo, drw, gflag,
                                    ch, ewo, ewq, ewk, ewv, wod);
  k_ow<<<(CG * CP + 127) / 128, 128, 0, stream>>>(out_w, gflag, owr, owi);
  k1_decomp<<<CB * CN, 256, 0, stream>>>(x, dec_w, dec_b, gflag, res, trend);
  k2_mlp<<<CB * CN, 256, 0, stream>>>(trend, mlp_w1, mlp_b1, mlp_w2, mlp_b2, mlp_w3, mlp_b3,
                                      gflag, trendo);
  k3_cem<<<CB * CT, 64, 0, stream>>>(res, ch, Pbuf);
  k4_qdft<<<CB * CN, 256, 0, stream>>>(Pbuf, Qbuf);
  k5_tem<<<CB * CN * CH, 256, 0, stream>>>(Qbuf, ewq, ewk, ewv, wod, Zp);
  k6_final<<<CB * CN, 128, 0, stream>>>(Zp, owr, owi, trendo, drb, out_b, wfuse, gflag, d_out);
}

// Round 3
// 462.110 us; speedup vs baseline: 1.6717x; 1.6717x over previous
//
#include <hip/hip_runtime.h>
#include <hip/hip_bf16.h>

typedef __hip_bfloat16 bf16;

constexpr int CB = 8;     // batch
constexpr int CT = 512;   // T
constexpr int CN = 64;    // N
constexpr int CD = 128;   // D
constexpr int CP = 96;    // PRED
constexpr int CH = 8;     // HEADS
constexpr int CDH = 16;   // head dim
constexpr int CHID = 256; // HID
constexpr int CM = 32;    // CEM freq tokens
constexpr int CG = 64;    // TEM freq tokens
constexpr float TWO_PI = 6.28318530717958647692f;

// dtype-agnostic load: f==true -> input is float32, else bf16
__device__ __forceinline__ float LD(const void* p, size_t i, bool f) {
  return f ? ((const float*)p)[i] : __bfloat162float(((const bf16*)p)[i]);
}

// ---------------- K_detect: decide fp32 vs bf16 from x's bit patterns --------------
__global__ void k_detect(const unsigned int* xw, float* flag) {
  __shared__ int cnt;
  if (threadIdx.x == 0) cnt = 0;
  __syncthreads();
  int c = 0;
  for (int i = threadIdx.x; i < 2048; i += 256) {
    unsigned int w = xw[i];
    unsigned int e = (w >> 7) & 0xFF; // exponent field of LOW 16-bit half as bf16
    if (e >= 0x90 || e <= 0x60) c++;
  }
  atomicAdd(&cnt, c);
  __syncthreads();
  if (threadIdx.x == 0) flag[0] = (cnt > 100) ? 1.f : 0.f;
}

// ---------------- K0a: emb projections, ch, wod, ewo (parallel, 512 thr) --------------
__global__ __launch_bounds__(512) void k0a(const void* emb, const void* cWq, const void* cWk,
                                           const void* cWv, const void* cWo, const void* tWo,
                                           const void* drw, const float* gflag,
                                           float* g_ch, float* g_ewo, float* g_wod) {
  bool f32 = gflag[0] != 0.f;
  __shared__ float eml[CD], drl[CD], eql[CD], ekl[CD], evl[CD];
  int tid = threadIdx.x;
  if (tid < 128) eml[tid] = LD(emb, tid, f32);
  else if (tid < 256) drl[tid - 128] = LD(drw, tid - 128, f32);
  __syncthreads();
  int grp = tid >> 7, e = tid & 127;
  if (grp < 3) {
    const void* W = grp == 0 ? cWq : (grp == 1 ? cWk : cWv);
    float a = 0;
    #pragma unroll 8
    for (int d = 0; d < CD; ++d) a += eml[d] * LD(W, d * CD + e, f32);
    (grp == 0 ? eql : (grp == 1 ? ekl : evl))[e] = a;
  } else {
    float a = 0;
    #pragma unroll 8
    for (int d = 0; d < CD; ++d) a += LD(tWo, e * CD + d, f32) * drl[d];
    g_wod[e] = a;
  }
  __syncthreads();
  if (tid < CH) {
    float c = 0;
    for (int j = 0; j < CDH; ++j) c += eql[tid * CDH + j] * ekl[tid * CDH + j];
    g_ch[tid] = fabsf(c);
  }
  {
    int h0 = grp * 2;
    for (int h = h0; h < h0 + 2; ++h) {
      float a = 0;
      #pragma unroll
      for (int j = 0; j < CDH; ++j) a += evl[h * CDH + j] * LD(cWo, (h * CDH + j) * CD + e, f32);
      g_ewo[h * CD + e] = a;
    }
  }
}

// ---------------- K0b: ewq/ewk/ewv = ewo @ tW{q,k,v}, one block per (which,h) ----------
__global__ __launch_bounds__(128) void k0b(const void* tWq, const void* tWk, const void* tWv,
                                           const float* gflag, const float* g_ewo,
                                           float* g_ewq, float* g_ewk, float* g_ewv) {
  bool f32 = gflag[0] != 0.f;
  __shared__ float ew[CD];
  int which = blockIdx.x >> 3, h = blockIdx.x & 7, e = threadIdx.x;
  ew[e] = g_ewo[h * CD + e];
  __syncthreads();
  const void* W = which == 0 ? tWq : (which == 1 ? tWk : tWv);
  float a = 0;
  #pragma unroll 8
  for (int d = 0; d < CD; ++d) a += ew[d] * LD(W, d * CD + e, f32);
  (which == 0 ? g_ewq : (which == 1 ? g_ewk : g_ewv))[h * CD + e] = a;
}

// ---------------- K0c: per-TEM-head 8x8 score matrix C_h and value vector u_h ----------
__global__ __launch_bounds__(128) void k0c(const float* g_ewq, const float* g_ewk,
                                           const float* g_ewv, const float* g_wod,
                                           float* g_C, float* g_u) {
  int h = blockIdx.x, tid = threadIdx.x;
  if (tid < 64) {
    int a = tid >> 3, b2 = tid & 7;
    float c = 0;
    #pragma unroll
    for (int j = 0; j < CDH; ++j)
      c += g_ewq[a * CD + h * CDH + j] * g_ewk[b2 * CD + h * CDH + j];
    g_C[(h * 8 + a) * 8 + b2] = c;
  } else if (tid < 72) {
    int a = tid - 64;
    float c = 0;
    #pragma unroll
    for (int j = 0; j < CDH; ++j) c += g_ewv[a * CD + h * CDH + j] * g_wod[h * CDH + j];
    g_u[h * 8 + a] = c;
  }
}

// ---------------- K_ow: Ow[g,p] = sum_t out_w[t,p] * e^{+2pi i g t/512}, 1 block/g ------
__global__ __launch_bounds__(128) void k_ow(const void* out_w, const float* gflag,
                                            float* owr, float* owi) {
  bool f32 = gflag[0] != 0.f;
  __shared__ float twc[CT], tws[CT];
  int g = blockIdx.x, tid = threadIdx.x; // 128
  for (int t = tid; t < CT; t += 128) {
    int k = (g * t) & (CT - 1);
    float s, c;
    sincosf((float)k * (TWO_PI / CT), &s, &c);
    twc[t] = c; tws[t] = s;
  }
  __syncthreads();
  if (tid < CP) {
    float sr = 0, si = 0;
    #pragma unroll 8
    for (int t = 0; t < CT; ++t) {
      float w = LD(out_w, t * CP + tid, f32);
      sr += w * twc[t]; si += w * tws[t];
    }
    owr[g * CP + tid] = sr; owi[g * CP + tid] = si;
  }
}

// ---------------- K1: decomposition (moving averages + 2-way softmax) --------------
__global__ void k1_decomp(const void* x, const void* dec_w, const void* dec_b, const float* gflag,
                          float* res, float* trend) {
  bool f32 = gflag[0] != 0.f;
  __shared__ float xl[CT];
  int blk = blockIdx.x;
  int b = blk >> 6, n = blk & 63;
  int tid = threadIdx.x; // 256
  size_t base = (size_t)b * CT * CN + n;
  xl[tid] = LD(x, base + (size_t)tid * CN, f32);
  xl[tid + 256] = LD(x, base + (size_t)(tid + 256) * CN, f32);
  __syncthreads();
  float w0 = LD(dec_w, 0, f32), w1 = LD(dec_w, 1, f32);
  float c0 = LD(dec_b, 0, f32), c1 = LD(dec_b, 1, f32);
  for (int t = tid; t < CT; t += 256) {
    float s17 = 0;
    for (int j = -8; j <= 8; ++j) {
      int u = t + j; u = u < 0 ? 0 : (u > CT - 1 ? CT - 1 : u);
      s17 += xl[u];
    }
    float s49 = 0;
    for (int j = -24; j <= 24; ++j) {
      int u = t + j; u = u < 0 ? 0 : (u > CT - 1 ? CT - 1 : u);
      s49 += xl[u];
    }
    float m0 = s17 * (1.f / 17.f), m1 = s49 * (1.f / 49.f);
    float xv = xl[t];
    float l0 = xv * w0 + c0, l1 = xv * w1 + c1;
    float mx = fmaxf(l0, l1);
    float e0 = __expf(l0 - mx), e1 = __expf(l1 - mx);
    float tr = (e0 * m0 + e1 * m1) / (e0 + e1);
    size_t o = ((size_t)(b * CT + t)) * CN + n;
    trend[o] = tr;
    res[o] = xv - tr;
  }
}

// ---------------- K2: trend MLP (512 -> 256 -> 256 -> 96 per (b,n) row) --------------
__global__ void k2_mlp(const float* trend, const void* w1, const void* bb1, const void* w2,
                       const void* bb2, const void* w3, const void* bb3, const float* gflag,
                       float* trendo) {
  bool f32 = gflag[0] != 0.f;
  __shared__ float rowl[CT], h1l[CHID], h2l[CHID];
  int blk = blockIdx.x;
  int b = blk >> 6, n = blk & 63;
  int tid = threadIdx.x; // 256
  const float* tb = trend + (size_t)b * CT * CN + n;
  rowl[tid] = tb[(size_t)tid * CN];
  rowl[tid + 256] = tb[(size_t)(tid + 256) * CN];
  __syncthreads();
  {
    float a = LD(bb1, tid, f32);
    #pragma unroll 8
    for (int t = 0; t < CT; ++t) a += rowl[t] * LD(w1, t * CHID + tid, f32);
    h1l[tid] = fmaxf(a, 0.f);
  }
  __syncthreads();
  {
    float a = LD(bb2, tid, f32);
    #pragma unroll 8
    for (int i = 0; i < CHID; ++i) a += h1l[i] * LD(w2, i * CHID + tid, f32);
    h2l[tid] = fmaxf(a, 0.f);
  }
  __syncthreads();
  if (tid < CP) {
    float a = LD(bb3, tid, f32);
    #pragma unroll 8
    for (int i = 0; i < CHID; ++i) a += h2l[i] * LD(w3, i * CP + tid, f32);
    trendo[((size_t)(b * CN + n)) * CP + tid] = a;
  }
}

// ---------------- K3: CEM collapsed attention -> P[b,t,h,n] --------------
__global__ __launch_bounds__(64) void k3_cem(const float* res, const float* g_ch, float* P) {
  __shared__ float rowl[CN], twc[CN], tws[CN];
  __shared__ float Rr[CM], Ri[CM], aR[CM];
  __shared__ float Sr[CH * CM], Si[CH * CM], chl[CH];
  int blk = blockIdx.x;
  int b = blk >> 9, t = blk & 511;
  int tid = threadIdx.x; // 64
  rowl[tid] = res[((size_t)(b * CT + t)) * CN + tid];
  {
    float s, c;
    sincosf((float)tid * (TWO_PI / CN), &s, &c);
    twc[tid] = c; tws[tid] = s;
  }
  if (tid < CH) chl[tid] = g_ch[tid];
  __syncthreads();
  if (tid < CM) {
    float rr = 0, ri = 0;
    int idx = 0;
    for (int n2 = 0; n2 < CN; ++n2) {
      rr += rowl[n2] * twc[idx];
      ri -= rowl[n2] * tws[idx];
      idx = (idx + tid) & (CN - 1);
    }
    Rr[tid] = rr; Ri[tid] = ri; aR[tid] = sqrtf(rr * rr + ri * ri);
  }
  __syncthreads();
  float amax = 0;
  for (int m = 0; m < CM; ++m) amax = fmaxf(amax, aR[m]);
  for (int i = 0; i < 4; ++i) {
    int pair = tid + 64 * i;
    int h = pair >> 5, m = pair & 31;
    float alpha = 0.25f * chl[h] * aR[m];
    float den = 0, sr = 0, si = 0;
    for (int n2 = 0; n2 < CM; ++n2) {
      float e = __expf(alpha * (aR[n2] - amax));
      den += e; sr += e * Rr[n2]; si += e * Ri[n2];
    }
    Sr[pair] = sr / den; Si[pair] = si / den;
  }
  __syncthreads();
  float* Pb = P + ((size_t)(b * CT + t)) * CH * CN;
  int n2 = tid;
  for (int h = 0; h < CH; ++h) {
    float a = Sr[h * CM]; // f = 0 term (Re only; imag dropped per irfft semantics)
    int idx = n2 & (CN - 1);
    #pragma unroll
    for (int f = 1; f < CM; ++f) {
      a += 2.f * (Sr[h * CM + f] * twc[idx] - Si[h * CM + f] * tws[idx]);
      idx = (idx + n2) & (CN - 1);
    }
    Pb[h * CN + n2] = a * (1.f / CN);
  }
}

// ---------------- K4: Q[b,n,g,h] = sum_t P[b,t,h,n] e^{-2pi i g t / 512} --------------
__global__ __launch_bounds__(256) void k4_qdft(const float* P, float* Q) {
  __shared__ float Pl[CT][CH];
  __shared__ float2 tw[CT];
  int blk = blockIdx.x;
  int b = blk >> 6, n = blk & 63;
  int tid = threadIdx.x; // 256
  for (int i = tid; i < CT * CH; i += 256) {
    int t = i >> 3, h = i & 7;
    Pl[t][h] = P[(((size_t)(b * CT + t)) * CH + h) * CN + n];
  }
  for (int i = tid; i < CT; i += 256) {
    float s, c;
    sincosf((float)i * (TWO_PI / CT), &s, &c);
    tw[i] = make_float2(c, s);
  }
  __syncthreads();
  int g1 = tid >> 3, h = tid & 7, g2 = g1 + 32;
  float r1 = 0, i1 = 0, r2 = 0, i2 = 0;
  int idx1 = 0, idx2 = 0;
  #pragma unroll 4
  for (int t = 0; t < CT; ++t) {
    float p = Pl[t][h];
    float2 w1 = tw[idx1], w2 = tw[idx2];
    r1 += p * w1.x; i1 -= p * w1.y;
    r2 += p * w2.x; i2 -= p * w2.y;
    idx1 = (idx1 + g1) & (CT - 1);
    idx2 = (idx2 + g2) & (CT - 1);
  }
  float* Qb = Q + ((size_t)(b * CN + n)) * CG * CH * 2;
  Qb[(g1 * CH + h) * 2] = r1; Qb[(g1 * CH + h) * 2 + 1] = i1;
  Qb[(g2 * CH + h) * 2] = r2; Qb[(g2 * CH + h) * 2 + 1] = i2;
}

// ---------------- K5: rank-8 TEM attention, all heads + head-sum + final output --------
// s[m,g] = |sum_b (Q8[m]·C_h)[b] * conj(Q8[g,b])|/4 ; z[m] = sum_g softmax(s)[m,g]*vd[g],
// vd[g] = Q8[g]·u_h. Then sum over h, inverse-DFT via Ow, fuse trend branch.
__global__ __launch_bounds__(512) void k5_tem(const float* Q, const float* g_C, const float* g_u,
                                              const float* owr, const float* owi,
                                              const float* trendo, const void* dr_b,
                                              const void* out_b, const void* wfuse,
                                              const float* gflag, void* out) {
  __shared__ float QL[CG][16];      // [g][a*2 + {re,im}]
  __shared__ float Cl[512];         // [h][a][b]
  __shared__ float Ul[CH][8];
  __shared__ float2 vdL[CH][CG];
  __shared__ float2 zL[CH][CG];
  __shared__ float zrow[CG][2];
  int blk = blockIdx.x;
  int b = blk >> 6, n = blk & 63;
  int tid = threadIdx.x; // 512
  const float* Qb = Q + ((size_t)(b * CN + n)) * CG * CH * 2;
  ((float2*)&QL[0][0])[tid] = ((const float2*)Qb)[tid];
  Cl[tid] = g_C[tid];
  if (tid < 64) ((float*)Ul)[tid] = g_u[tid];
  __syncthreads();
  int h = tid >> 6, m = tid & 63;
  // own row fragments
  const float4* q4 = (const float4*)QL[m];
  float4 x0 = q4[0], x1 = q4[1], x2 = q4[2], x3 = q4[3];
  float ar[8] = {x0.x, x0.z, x1.x, x1.z, x2.x, x2.z, x3.x, x3.z};
  float ai[8] = {x0.y, x0.w, x1.y, x1.w, x2.y, x2.w, x3.y, x3.w};
  // vd[h][m] = Q8[m] . u_h
  {
    float vr = 0, vi = 0;
    #pragma unroll
    for (int a = 0; a < 8; ++a) { float u = Ul[h][a]; vr += ar[a] * u; vi += ai[a] * u; }
    vdL[h][m] = make_float2(vr, vi);
  }
  // Qt = Q8[m] . C_h  (real C)
  float qtr[8], qti[8];
  #pragma unroll
  for (int bb = 0; bb < 8; ++bb) {
    float sr = 0, si = 0;
    #pragma unroll
    for (int a = 0; a < 8; ++a) {
      float c = Cl[(h * 8 + a) * 8 + bb];
      sr += ar[a] * c; si += ai[a] * c;
    }
    qtr[bb] = sr; qti[bb] = si;
  }
  // scores (kept in registers)
  float sv[CG];
  float mx = -1e30f;
  #pragma unroll
  for (int g = 0; g < CG; ++g) {
    const float4* k4p = (const float4*)QL[g];
    float4 y0 = k4p[0], y1 = k4p[1], y2 = k4p[2], y3 = k4p[3];
    float sr = qtr[0] * y0.x + qti[0] * y0.y + qtr[1] * y0.z + qti[1] * y0.w
             + qtr[2] * y1.x + qti[2] * y1.y + qtr[3] * y1.z + qti[3] * y1.w
             + qtr[4] * y2.x + qti[4] * y2.y + qtr[5] * y2.z + qti[5] * y2.w
             + qtr[6] * y3.x + qti[6] * y3.y + qtr[7] * y3.z + qti[7] * y3.w;
    float si = qti[0] * y0.x - qtr[0] * y0.y + qti[1] * y0.z - qtr[1] * y0.w
             + qti[2] * y1.x - qtr[2] * y1.y + qti[3] * y1.z - qtr[3] * y1.w
             + qti[4] * y2.x - qtr[4] * y2.y + qti[5] * y2.z - qtr[5] * y2.w
             + qti[6] * y3.x - qtr[6] * y3.y + qti[7] * y3.z - qtr[7] * y3.w;
    float s = 0.25f * sqrtf(sr * sr + si * si);
    sv[g] = s; mx = fmaxf(mx, s);
  }
  __syncthreads(); // vdL visible
  float den = 0;
  #pragma unroll
  for (int g = 0; g < CG; ++g) { float e = __expf(sv[g] - mx); sv[g] = e; den += e; }
  float rv = 1.f / den;
  float zr = 0, zi = 0;
  #pragma unroll
  for (int g = 0; g < CG; ++g) {
    float2 vd = vdL[h][g];
    zr += sv[g] * vd.x; zi += sv[g] * vd.y;
  }
  zL[h][m] = make_float2(zr * rv, zi * rv);
  __syncthreads();
  if (tid < 128) {
    int g = tid >> 1, c = tid & 1;
    float a = 0;
    #pragma unroll
    for (int hh = 0; hh < CH; ++hh) a += c ? zL[hh][g].y : zL[hh][g].x;
    zrow[g][c] = a;
  }
  __syncthreads();
  if (tid < CP) {
    bool f32 = gflag[0] != 0.f;
    int p = tid;
    float acc = zrow[0][0] * owr[p] - zrow[0][1] * owi[p];
    #pragma unroll 8
    for (int g = 1; g < CG; ++g)
      acc += 2.f * (zrow[g][0] * owr[g * CP + p] - zrow[g][1] * owi[g * CP + p]);
    float xo = acc * (1.f / CT) + LD(dr_b, 0, f32) * owr[p] + LD(out_b, p, f32);
    float val = LD(wfuse, 0, f32) * xo + LD(wfuse, 1, f32) * trendo[((size_t)(b * CN + n)) * CP + p];
    size_t oidx = ((size_t)(b * CP + p)) * CN + n;
    if (f32) ((float*)out)[oidx] = val;
    else ((bf16*)out)[oidx] = __float2bfloat16(val);
  }
}

extern "C" void kernel_launch(void* const* d_in, const int* in_sizes, int n_in,
                              void* d_out, int out_size, void* d_ws, size_t ws_size,
                              hipStream_t stream) {
  const void* x = d_in[0];
  const void* emb = d_in[1];
  const void* dec_w = d_in[2];
  const void* dec_b = d_in[3];
  const void* mlp_w1 = d_in[4];
  const void* mlp_b1 = d_in[5];
  const void* mlp_w2 = d_in[6];
  const void* mlp_b2 = d_in[7];
  const void* mlp_w3 = d_in[8];
  const void* mlp_b3 = d_in[9];
  const void* cWq = d_in[10];
  const void* cWk = d_in[11];
  const void* cWv = d_in[12];
  const void* cWo = d_in[13];
  const void* tWq = d_in[14];
  const void* tWk = d_in[15];
  const void* tWv = d_in[16];
  const void* tWo = d_in[17];
  const void* drw = d_in[18];
  const void* drb = d_in[19];
  const void* out_w = d_in[20];
  const void* out_b = d_in[21];
  const void* wfuse = d_in[22];

  float* W = (float*)d_ws;
  float* res = W;    W += (size_t)CB * CT * CN;
  float* trend = W;  W += (size_t)CB * CT * CN;
  float* trendo = W; W += (size_t)CB * CN * CP;
  float* Pbuf = W;   W += (size_t)CB * CT * CH * CN;
  float* Qbuf = W;   W += (size_t)CB * CN * CG * CH * 2;
  float* ch = W;     W += 8;
  float* ewo = W;    W += CH * CD;
  float* ewq = W;    W += CH * CD;
  float* ewk = W;    W += CH * CD;
  float* ewv = W;    W += CH * CD;
  float* wod = W;    W += CD;
  float* owr = W;    W += CG * CP;
  float* owi = W;    W += CG * CP;
  float* gC = W;     W += 512;
  float* gU = W;     W += 64;
  float* gflag = W;  W += 64;

  k_detect<<<1, 256, 0, stream>>>((const unsigned int*)x, gflag);
  k0a<<<1, 512, 0, stream>>>(emb, cWq, cWk, cWv, cWo, tWo, drw, gflag, ch, ewo, wod);
  k0b<<<24, 128, 0, stream>>>(tWq, tWk, tWv, gflag, ewo, ewq, ewk, ewv);
  k0c<<<8, 128, 0, stream>>>(ewq, ewk, ewv, wod, gC, gU);
  k_ow<<<CG, 128, 0, stream>>>(out_w, gflag, owr, owi);
  k1_decomp<<<CB * CN, 256, 0, stream>>>(x, dec_w, dec_b, gflag, res, trend);
  k2_mlp<<<CB * CN, 256, 0, stream>>>(trend, mlp_w1, mlp_b1, mlp_w2, mlp_b2, mlp_w3, mlp_b3,
                                      gflag, trendo);
  k3_cem<<<CB * CT, 64, 0, stream>>>(res, ch, Pbuf);
  k4_qdft<<<CB * CN, 256, 0, stream>>>(Pbuf, Qbuf);
  k5_tem<<<CB * CN, 512, 0, stream>>>(Qbuf, gC, gU, owr, owi, trendo, drb, out_b, wfuse,
                                      gflag, d_out);
}

// Round 4
// 444.203 us; speedup vs baseline: 1.7391x; 1.0403x over previous
//
#include <hip/hip_runtime.h>
#include <hip/hip_bf16.h>

typedef __hip_bfloat16 bf16;

constexpr int CB = 8;     // batch
constexpr int CT = 512;   // T
constexpr int CN = 64;    // N
constexpr int CD = 128;   // D
constexpr int CP = 96;    // PRED
constexpr int CH = 8;     // HEADS
constexpr int CDH = 16;   // head dim
constexpr int CHID = 256; // HID
constexpr int CM = 32;    // CEM freq tokens
constexpr int CG = 64;    // TEM freq tokens
constexpr float TWO_PI = 6.28318530717958647692f;

// dtype-agnostic load: f==true -> input is float32, else bf16
__device__ __forceinline__ float LD(const void* p, size_t i, bool f) {
  return f ? ((const float*)p)[i] : __bfloat162float(((const bf16*)p)[i]);
}

// ---------------- K_detect: decide fp32 vs bf16 from x's bit patterns --------------
__global__ void k_detect(const unsigned int* xw, float* flag) {
  __shared__ int cnt;
  if (threadIdx.x == 0) cnt = 0;
  __syncthreads();
  int c = 0;
  for (int i = threadIdx.x; i < 2048; i += 256) {
    unsigned int w = xw[i];
    unsigned int e = (w >> 7) & 0xFF; // exponent field of LOW 16-bit half as bf16
    if (e >= 0x90 || e <= 0x60) c++;
  }
  atomicAdd(&cnt, c);
  __syncthreads();
  if (threadIdx.x == 0) flag[0] = (cnt > 100) ? 1.f : 0.f;
}

// ---------------- K0a: emb projections, ch, wod, ewo (parallel, 512 thr) --------------
__global__ __launch_bounds__(512) void k0a(const void* emb, const void* cWq, const void* cWk,
                                           const void* cWv, const void* cWo, const void* tWo,
                                           const void* drw, const float* gflag,
                                           float* g_ch, float* g_ewo, float* g_wod) {
  bool f32 = gflag[0] != 0.f;
  __shared__ float eml[CD], drl[CD], eql[CD], ekl[CD], evl[CD];
  int tid = threadIdx.x;
  if (tid < 128) eml[tid] = LD(emb, tid, f32);
  else if (tid < 256) drl[tid - 128] = LD(drw, tid - 128, f32);
  __syncthreads();
  int grp = tid >> 7, e = tid & 127;
  if (grp < 3) {
    const void* W = grp == 0 ? cWq : (grp == 1 ? cWk : cWv);
    float a = 0;
    #pragma unroll 8
    for (int d = 0; d < CD; ++d) a += eml[d] * LD(W, d * CD + e, f32);
    (grp == 0 ? eql : (grp == 1 ? ekl : evl))[e] = a;
  } else {
    float a = 0;
    #pragma unroll 8
    for (int d = 0; d < CD; ++d) a += LD(tWo, e * CD + d, f32) * drl[d];
    g_wod[e] = a;
  }
  __syncthreads();
  if (tid < CH) {
    float c = 0;
    for (int j = 0; j < CDH; ++j) c += eql[tid * CDH + j] * ekl[tid * CDH + j];
    g_ch[tid] = fabsf(c);
  }
  {
    int h0 = grp * 2;
    for (int h = h0; h < h0 + 2; ++h) {
      float a = 0;
      #pragma unroll
      for (int j = 0; j < CDH; ++j) a += evl[h * CDH + j] * LD(cWo, (h * CDH + j) * CD + e, f32);
      g_ewo[h * CD + e] = a;
    }
  }
}

// ---------------- K0b: ewq/ewk/ewv = ewo @ tW{q,k,v}, one block per (which,h) ----------
__global__ __launch_bounds__(128) void k0b(const void* tWq, const void* tWk, const void* tWv,
                                           const float* gflag, const float* g_ewo,
                                           float* g_ewq, float* g_ewk, float* g_ewv) {
  bool f32 = gflag[0] != 0.f;
  __shared__ float ew[CD];
  int which = blockIdx.x >> 3, h = blockIdx.x & 7, e = threadIdx.x;
  ew[e] = g_ewo[h * CD + e];
  __syncthreads();
  const void* W = which == 0 ? tWq : (which == 1 ? tWk : tWv);
  float a = 0;
  #pragma unroll 8
  for (int d = 0; d < CD; ++d) a += ew[d] * LD(W, d * CD + e, f32);
  (which == 0 ? g_ewq : (which == 1 ? g_ewk : g_ewv))[h * CD + e] = a;
}

// ---------------- K0c: per-TEM-head 8x8 score matrix C_h and value vector u_h ----------
__global__ __launch_bounds__(128) void k0c(const float* g_ewq, const float* g_ewk,
                                           const float* g_ewv, const float* g_wod,
                                           float* g_C, float* g_u) {
  int h = blockIdx.x, tid = threadIdx.x;
  if (tid < 64) {
    int a = tid >> 3, b2 = tid & 7;
    float c = 0;
    #pragma unroll
    for (int j = 0; j < CDH; ++j)
      c += g_ewq[a * CD + h * CDH + j] * g_ewk[b2 * CD + h * CDH + j];
    g_C[(h * 8 + a) * 8 + b2] = c;
  } else if (tid < 72) {
    int a = tid - 64;
    float c = 0;
    #pragma unroll
    for (int j = 0; j < CDH; ++j) c += g_ewv[a * CD + h * CDH + j] * g_wod[h * CDH + j];
    g_u[h * 8 + a] = c;
  }
}

// ---------------- K_ow: Ow[g,p] = sum_t out_w[t,p] * e^{+2pi i g t/512}, 1 block/g ------
__global__ __launch_bounds__(128) void k_ow(const void* out_w, const float* gflag,
                                            float* owr, float* owi) {
  bool f32 = gflag[0] != 0.f;
  __shared__ float twc[CT], tws[CT];
  int g = blockIdx.x, tid = threadIdx.x; // 128
  for (int t = tid; t < CT; t += 128) {
    int k = (g * t) & (CT - 1);
    float s, c;
    sincosf((float)k * (TWO_PI / CT), &s, &c);
    twc[t] = c; tws[t] = s;
  }
  __syncthreads();
  if (tid < CP) {
    float sr = 0, si = 0;
    #pragma unroll 8
    for (int t = 0; t < CT; ++t) {
      float w = LD(out_w, t * CP + tid, f32);
      sr += w * twc[t]; si += w * tws[t];
    }
    owr[g * CP + tid] = sr; owi[g * CP + tid] = si;
  }
}

// ---------------- K1: decomposition, coalesced 512x16 tiles --------------
__global__ __launch_bounds__(256) void k1_decomp(const void* x, const void* dec_w,
                                                 const void* dec_b, const float* gflag,
                                                 float* res, float* trend) {
  bool f32 = gflag[0] != 0.f;
  __shared__ float xl[CT][17]; // +1 pad
  int b = blockIdx.x >> 2, n0 = (blockIdx.x & 3) * 16;
  int tid = threadIdx.x; // 256
  size_t base = (size_t)b * CT * CN + n0;
  for (int i = tid; i < CT * 16; i += 256) {
    int t = i >> 4, j = i & 15;
    xl[t][j] = LD(x, base + (size_t)t * CN + j, f32);
  }
  __syncthreads();
  float w0 = LD(dec_w, 0, f32), w1 = LD(dec_w, 1, f32);
  float c0 = LD(dec_b, 0, f32), c1 = LD(dec_b, 1, f32);
  int j = tid & 15, tl = tid >> 4; // 16 t-lanes x 16 cols
  for (int k = 0; k < CT / 16; ++k) {
    int t = k * 16 + tl;
    float s17 = 0;
    #pragma unroll
    for (int o = -8; o <= 8; ++o) {
      int u = t + o; u = u < 0 ? 0 : (u > CT - 1 ? CT - 1 : u);
      s17 += xl[u][j];
    }
    float s49 = 0;
    #pragma unroll
    for (int o = -24; o <= 24; ++o) {
      int u = t + o; u = u < 0 ? 0 : (u > CT - 1 ? CT - 1 : u);
      s49 += xl[u][j];
    }
    float m0 = s17 * (1.f / 17.f), m1 = s49 * (1.f / 49.f);
    float xv = xl[t][j];
    float l0 = xv * w0 + c0, l1 = xv * w1 + c1;
    float mx = fmaxf(l0, l1);
    float e0 = __expf(l0 - mx), e1 = __expf(l1 - mx);
    float tr = (e0 * m0 + e1 * m1) / (e0 + e1);
    size_t o = ((size_t)(b * CT + t)) * CN + n0 + j;
    trend[o] = tr;
    res[o] = xv - tr;
  }
}

// ---------------- K2: trend MLP, 8 rows per block (weight amortization) --------------
__global__ __launch_bounds__(256) void k2_mlp(const float* trend, const void* w1, const void* bb1,
                                              const void* w2, const void* bb2, const void* w3,
                                              const void* bb3, const float* gflag, float* trendo) {
  bool f32 = gflag[0] != 0.f;
  __shared__ float rows[8][CT + 8];
  __shared__ float h1[8][CHID];
  __shared__ float h2[8][CHID];
  int r0 = blockIdx.x * 8; // 64 blocks
  int b = r0 >> 6, n0 = r0 & 63;
  int tid = threadIdx.x; // 256
  const float* tb = trend + (size_t)b * CT * CN + n0;
  for (int i = tid; i < 8 * CT; i += 256) {
    int q = i & 7, t = i >> 3;
    rows[q][t] = tb[(size_t)t * CN + q];
  }
  __syncthreads();
  float acc[8];
  {
    float bias = LD(bb1, tid, f32);
    #pragma unroll
    for (int q = 0; q < 8; ++q) acc[q] = bias;
    #pragma unroll 4
    for (int t = 0; t < CT; ++t) {
      float w = LD(w1, t * CHID + tid, f32);
      #pragma unroll
      for (int q = 0; q < 8; ++q) acc[q] += rows[q][t] * w;
    }
    #pragma unroll
    for (int q = 0; q < 8; ++q) h1[q][tid] = fmaxf(acc[q], 0.f);
  }
  __syncthreads();
  {
    float bias = LD(bb2, tid, f32);
    #pragma unroll
    for (int q = 0; q < 8; ++q) acc[q] = bias;
    #pragma unroll 4
    for (int i = 0; i < CHID; ++i) {
      float w = LD(w2, i * CHID + tid, f32);
      #pragma unroll
      for (int q = 0; q < 8; ++q) acc[q] += h1[q][i] * w;
    }
    #pragma unroll
    for (int q = 0; q < 8; ++q) h2[q][tid] = fmaxf(acc[q], 0.f);
  }
  __syncthreads();
  for (int pair = tid; pair < 8 * CP; pair += 256) {
    int q = pair / CP, p = pair - q * CP;
    float a = LD(bb3, p, f32);
    #pragma unroll 4
    for (int i = 0; i < CHID; ++i) a += h2[q][i] * LD(w3, i * CP + p, f32);
    trendo[((size_t)(b * CN + n0 + q)) * CP + p] = a;
  }
}

// ---------------- K3: CEM collapsed attention -> P[b,t,h,n] --------------
__global__ __launch_bounds__(64) void k3_cem(const float* res, const float* g_ch, float* P) {
  __shared__ float rowl[CN], twc[CN], tws[CN];
  __shared__ float Rr[CM], Ri[CM], aR[CM];
  __shared__ float Sr[CH * CM], Si[CH * CM], chl[CH];
  int blk = blockIdx.x;
  int b = blk >> 9, t = blk & 511;
  int tid = threadIdx.x; // 64
  rowl[tid] = res[((size_t)(b * CT + t)) * CN + tid];
  {
    float s, c;
    sincosf((float)tid * (TWO_PI / CN), &s, &c);
    twc[tid] = c; tws[tid] = s;
  }
  if (tid < CH) chl[tid] = g_ch[tid];
  __syncthreads();
  if (tid < CM) {
    float rr = 0, ri = 0;
    int idx = 0;
    for (int n2 = 0; n2 < CN; ++n2) {
      rr += rowl[n2] * twc[idx];
      ri -= rowl[n2] * tws[idx];
      idx = (idx + tid) & (CN - 1);
    }
    Rr[tid] = rr; Ri[tid] = ri; aR[tid] = sqrtf(rr * rr + ri * ri);
  }
  __syncthreads();
  float amax = 0;
  for (int m = 0; m < CM; ++m) amax = fmaxf(amax, aR[m]);
  for (int i = 0; i < 4; ++i) {
    int pair = tid + 64 * i;
    int h = pair >> 5, m = pair & 31;
    float alpha = 0.25f * chl[h] * aR[m];
    float den = 0, sr = 0, si = 0;
    for (int n2 = 0; n2 < CM; ++n2) {
      float e = __expf(alpha * (aR[n2] - amax));
      den += e; sr += e * Rr[n2]; si += e * Ri[n2];
    }
    Sr[pair] = sr / den; Si[pair] = si / den;
  }
  __syncthreads();
  float* Pb = P + ((size_t)(b * CT + t)) * CH * CN;
  int n2 = tid;
  for (int h = 0; h < CH; ++h) {
    float a = Sr[h * CM]; // f = 0 term (Re only; imag dropped per irfft semantics)
    int idx = n2 & (CN - 1);
    #pragma unroll
    for (int f = 1; f < CM; ++f) {
      a += 2.f * (Sr[h * CM + f] * twc[idx] - Si[h * CM + f] * tws[idx]);
      idx = (idx + n2) & (CN - 1);
    }
    Pb[h * CN + n2] = a * (1.f / CN);
  }
}

// ---------------- K4: Q[b,n,g,h] = sum_t P[b,t,h,n] e^{-2pi i g t / 512} --------------
// Twiddles via per-thread incremental complex rotation (no LDS in inner loop).
__global__ __launch_bounds__(256) void k4_qdft(const float* P, float* Q) {
  __shared__ float Pl[CT][CH];
  int blk = blockIdx.x;
  int b = blk >> 6, n = blk & 63;
  int tid = threadIdx.x; // 256
  for (int i = tid; i < CT * CH; i += 256) {
    int t = i >> 3, h = i & 7;
    Pl[t][h] = P[(((size_t)(b * CT + t)) * CH + h) * CN + n];
  }
  __syncthreads();
  int g1 = tid >> 3, h = tid & 7, g2 = g1 + 32;
  float s1, c1, s2, c2;
  sincosf((float)g1 * (TWO_PI / CT), &s1, &c1);
  sincosf((float)g2 * (TWO_PI / CT), &s2, &c2);
  float wr1 = 1.f, wi1 = 0.f, wr2 = 1.f, wi2 = 0.f;
  float r1 = 0, i1 = 0, r2 = 0, i2 = 0;
  #pragma unroll 8
  for (int t = 0; t < CT; ++t) {
    float p = Pl[t][h];
    r1 += p * wr1; i1 += p * wi1;
    r2 += p * wr2; i2 += p * wi2;
    // w *= e^{-2pi i g/512}: (wr + i wi)(c - i s)
    float nr1 = wr1 * c1 + wi1 * s1; wi1 = wi1 * c1 - wr1 * s1; wr1 = nr1;
    float nr2 = wr2 * c2 + wi2 * s2; wi2 = wi2 * c2 - wr2 * s2; wr2 = nr2;
  }
  float* Qb = Q + ((size_t)(b * CN + n)) * CG * CH * 2;
  Qb[(g1 * CH + h) * 2] = r1; Qb[(g1 * CH + h) * 2 + 1] = i1;
  Qb[(g2 * CH + h) * 2] = r2; Qb[(g2 * CH + h) * 2 + 1] = i2;
}

// ---------------- K5: rank-8 TEM attention, online softmax (no sv[] spill) --------
__global__ __launch_bounds__(512) void k5_tem(const float* Q, const float* g_C, const float* g_u,
                                              const float* owr, const float* owi,
                                              const float* trendo, const void* dr_b,
                                              const void* out_b, const void* wfuse,
                                              const float* gflag, void* out) {
  __shared__ float QL[CG][16];      // [g][a*2 + {re,im}]
  __shared__ float Cl[512];         // [h][a][b]
  __shared__ float Ul[CH][8];
  __shared__ float2 vdL[CH][CG];
  __shared__ float2 zL[CH][CG];
  __shared__ float zrow[CG][2];
  int blk = blockIdx.x;
  int b = blk >> 6, n = blk & 63;
  int tid = threadIdx.x; // 512
  const float* Qb = Q + ((size_t)(b * CN + n)) * CG * CH * 2;
  ((float2*)&QL[0][0])[tid] = ((const float2*)Qb)[tid];
  Cl[tid] = g_C[tid];
  if (tid < 64) ((float*)Ul)[tid] = g_u[tid];
  __syncthreads();
  int h = tid >> 6, m = tid & 63;
  const float4* q4 = (const float4*)QL[m];
  float4 x0 = q4[0], x1 = q4[1], x2 = q4[2], x3 = q4[3];
  float ar[8] = {x0.x, x0.z, x1.x, x1.z, x2.x, x2.z, x3.x, x3.z};
  float ai[8] = {x0.y, x0.w, x1.y, x1.w, x2.y, x2.w, x3.y, x3.w};
  // vd[h][m] = Q8[m] . u_h
  {
    float vr = 0, vi = 0;
    #pragma unroll
    for (int a = 0; a < 8; ++a) { float u = Ul[h][a]; vr += ar[a] * u; vi += ai[a] * u; }
    vdL[h][m] = make_float2(vr, vi);
  }
  // Qt = Q8[m] . C_h (real C)
  float qtr[8], qti[8];
  #pragma unroll
  for (int bb = 0; bb < 8; ++bb) {
    float sr = 0, si = 0;
    #pragma unroll
    for (int a = 0; a < 8; ++a) {
      float c = Cl[(h * 8 + a) * 8 + bb];
      sr += ar[a] * c; si += ai[a] * c;
    }
    qtr[bb] = sr; qti[bb] = si;
  }
  __syncthreads(); // vdL visible
  // fused scores + online softmax + z accumulation (zero register arrays over g)
  float mx = -1e30f, den = 0.f, zr = 0.f, zi = 0.f;
  #pragma unroll 4
  for (int g = 0; g < CG; ++g) {
    const float4* k4p = (const float4*)QL[g];
    float4 y0 = k4p[0], y1 = k4p[1], y2 = k4p[2], y3 = k4p[3];
    float sr = qtr[0] * y0.x + qti[0] * y0.y + qtr[1] * y0.z + qti[1] * y0.w
             + qtr[2] * y1.x + qti[2] * y1.y + qtr[3] * y1.z + qti[3] * y1.w
             + qtr[4] * y2.x + qti[4] * y2.y + qtr[5] * y2.z + qti[5] * y2.w
             + qtr[6] * y3.x + qti[6] * y3.y + qtr[7] * y3.z + qti[7] * y3.w;
    float si = qti[0] * y0.x - qtr[0] * y0.y + qti[1] * y0.z - qtr[1] * y0.w
             + qti[2] * y1.x - qtr[2] * y1.y + qti[3] * y1.z - qtr[3] * y1.w
             + qti[4] * y2.x - qtr[4] * y2.y + qti[5] * y2.z - qtr[5] * y2.w
             + qti[6] * y3.x - qtr[6] * y3.y + qti[7] * y3.z - qtr[7] * y3.w;
    float s = 0.25f * sqrtf(sr * sr + si * si);
    if (s > mx) {
      float f = __expf(mx - s);
      den *= f; zr *= f; zi *= f; mx = s;
    }
    float e = __expf(s - mx);
    float2 vd = vdL[h][g];
    den += e; zr += e * vd.x; zi += e * vd.y;
  }
  float rv = 1.f / den;
  zL[h][m] = make_float2(zr * rv, zi * rv);
  __syncthreads();
  if (tid < 128) {
    int g = tid >> 1, c = tid & 1;
    float a = 0;
    #pragma unroll
    for (int hh = 0; hh < CH; ++hh) a += c ? zL[hh][g].y : zL[hh][g].x;
    zrow[g][c] = a;
  }
  __syncthreads();
  if (tid < CP) {
    bool f32 = gflag[0] != 0.f;
    int p = tid;
    float acc = zrow[0][0] * owr[p] - zrow[0][1] * owi[p];
    #pragma unroll 8
    for (int g = 1; g < CG; ++g)
      acc += 2.f * (zrow[g][0] * owr[g * CP + p] - zrow[g][1] * owi[g * CP + p]);
    float xo = acc * (1.f / CT) + LD(dr_b, 0, f32) * owr[p] + LD(out_b, p, f32);
    float val = LD(wfuse, 0, f32) * xo + LD(wfuse, 1, f32) * trendo[((size_t)(b * CN + n)) * CP + p];
    size_t oidx = ((size_t)(b * CP + p)) * CN + n;
    if (f32) ((float*)out)[oidx] = val;
    else ((bf16*)out)[oidx] = __float2bfloat16(val);
  }
}

extern "C" void kernel_launch(void* const* d_in, const int* in_sizes, int n_in,
                              void* d_out, int out_size, void* d_ws, size_t ws_size,
                              hipStream_t stream) {
  const void* x = d_in[0];
  const void* emb = d_in[1];
  const void* dec_w = d_in[2];
  const void* dec_b = d_in[3];
  const void* mlp_w1 = d_in[4];
  const void* mlp_b1 = d_in[5];
  const void* mlp_w2 = d_in[6];
  const void* mlp_b2 = d_in[7];
  const void* mlp_w3 = d_in[8];
  const void* mlp_b3 = d_in[9];
  const void* cWq = d_in[10];
  const void* cWk = d_in[11];
  const void* cWv = d_in[12];
  const void* cWo = d_in[13];
  const void* tWq = d_in[14];
  const void* tWk = d_in[15];
  const void* tWv = d_in[16];
  const void* tWo = d_in[17];
  const void* drw = d_in[18];
  const void* drb = d_in[19];
  const void* out_w = d_in[20];
  const void* out_b = d_in[21];
  const void* wfuse = d_in[22];

  float* W = (float*)d_ws;
  float* res = W;    W += (size_t)CB * CT * CN;
  float* trend = W;  W += (size_t)CB * CT * CN;
  float* trendo = W; W += (size_t)CB * CN * CP;
  float* Pbuf = W;   W += (size_t)CB * CT * CH * CN;
  float* Qbuf = W;   W += (size_t)CB * CN * CG * CH * 2;
  float* ch = W;     W += 8;
  float* ewo = W;    W += CH * CD;
  float* ewq = W;    W += CH * CD;
  float* ewk = W;    W += CH * CD;
  float* ewv = W;    W += CH * CD;
  float* wod = W;    W += CD;
  float* owr = W;    W += CG * CP;
  float* owi = W;    W += CG * CP;
  float* gC = W;     W += 512;
  float* gU = W;     W += 64;
  float* gflag = W;  W += 64;

  k_detect<<<1, 256, 0, stream>>>((const unsigned int*)x, gflag);
  k0a<<<1, 512, 0, stream>>>(emb, cWq, cWk, cWv, cWo, tWo, drw, gflag, ch, ewo, wod);
  k0b<<<24, 128, 0, stream>>>(tWq, tWk, tWv, gflag, ewo, ewq, ewk, ewv);
  k0c<<<8, 128, 0, stream>>>(ewq, ewk, ewv, wod, gC, gU);
  k_ow<<<CG, 128, 0, stream>>>(out_w, gflag, owr, owi);
  k1_decomp<<<CB * 4, 256, 0, stream>>>(x, dec_w, dec_b, gflag, res, trend);
  k2_mlp<<<CB * CN / 8, 256, 0, stream>>>(trend, mlp_w1, mlp_b1, mlp_w2, mlp_b2, mlp_w3, mlp_b3,
                                          gflag, trendo);
  k3_cem<<<CB * CT, 64, 0, stream>>>(res, ch, Pbuf);
  k4_qdft<<<CB * CN, 256, 0, stream>>>(Pbuf, Qbuf);
  k5_tem<<<CB * CN, 512, 0, stream>>>(Qbuf, gC, gU, owr, owi, trendo, drb, out_b, wfuse,
                                      gflag, d_out);
}

// Round 5
// 332.003 us; speedup vs baseline: 2.3269x; 1.3380x over previous
//
#include <hip/hip_runtime.h>
#include <hip/hip_bf16.h>

typedef __hip_bfloat16 bf16;

constexpr int CB = 8;     // batch
constexpr int CT = 512;   // T
constexpr int CN = 64;    // N
constexpr int CD = 128;   // D
constexpr int CP = 96;    // PRED
constexpr int CH = 8;     // HEADS
constexpr int CDH = 16;   // head dim
constexpr int CHID = 256; // HID
constexpr int CM = 32;    // CEM freq tokens
constexpr int CG = 64;    // TEM freq tokens
constexpr float TWO_PI = 6.28318530717958647692f;

// dtype-agnostic load: f==true -> input is float32, else bf16
__device__ __forceinline__ float LD(const void* p, size_t i, bool f) {
  return f ? ((const float*)p)[i] : __bfloat162float(((const bf16*)p)[i]);
}
template <bool F32>
__device__ __forceinline__ float LDT(const void* p, size_t i) {
  return F32 ? ((const float*)p)[i] : __bfloat162float(((const bf16*)p)[i]);
}

// ---------------- K_detect: decide fp32 vs bf16 from x's bit patterns --------------
__global__ void k_detect(const unsigned int* xw, float* flag) {
  __shared__ int cnt;
  if (threadIdx.x == 0) cnt = 0;
  __syncthreads();
  int c = 0;
  for (int i = threadIdx.x; i < 2048; i += 256) {
    unsigned int w = xw[i];
    unsigned int e = (w >> 7) & 0xFF; // exponent field of LOW 16-bit half as bf16
    if (e >= 0x90 || e <= 0x60) c++;
  }
  atomicAdd(&cnt, c);
  __syncthreads();
  if (threadIdx.x == 0) flag[0] = (cnt > 100) ? 1.f : 0.f;
}

// ---------------- K0a: emb projections, ch, wod, ewo (parallel, 512 thr) --------------
__global__ __launch_bounds__(512) void k0a(const void* emb, const void* cWq, const void* cWk,
                                           const void* cWv, const void* cWo, const void* tWo,
                                           const void* drw, const float* gflag,
                                           float* g_ch, float* g_ewo, float* g_wod) {
  bool f32 = gflag[0] != 0.f;
  __shared__ float eml[CD], drl[CD], eql[CD], ekl[CD], evl[CD];
  int tid = threadIdx.x;
  if (tid < 128) eml[tid] = LD(emb, tid, f32);
  else if (tid < 256) drl[tid - 128] = LD(drw, tid - 128, f32);
  __syncthreads();
  int grp = tid >> 7, e = tid & 127;
  if (grp < 3) {
    const void* W = grp == 0 ? cWq : (grp == 1 ? cWk : cWv);
    float a = 0;
    #pragma unroll 8
    for (int d = 0; d < CD; ++d) a += eml[d] * LD(W, d * CD + e, f32);
    (grp == 0 ? eql : (grp == 1 ? ekl : evl))[e] = a;
  } else {
    float a = 0;
    #pragma unroll 8
    for (int d = 0; d < CD; ++d) a += LD(tWo, e * CD + d, f32) * drl[d];
    g_wod[e] = a;
  }
  __syncthreads();
  if (tid < CH) {
    float c = 0;
    for (int j = 0; j < CDH; ++j) c += eql[tid * CDH + j] * ekl[tid * CDH + j];
    g_ch[tid] = fabsf(c);
  }
  {
    int h0 = grp * 2;
    for (int h = h0; h < h0 + 2; ++h) {
      float a = 0;
      #pragma unroll
      for (int j = 0; j < CDH; ++j) a += evl[h * CDH + j] * LD(cWo, (h * CDH + j) * CD + e, f32);
      g_ewo[h * CD + e] = a;
    }
  }
}

// ---------------- K0b: ewq/ewk/ewv = ewo @ tW{q,k,v}, one block per (which,h) ----------
__global__ __launch_bounds__(128) void k0b(const void* tWq, const void* tWk, const void* tWv,
                                           const float* gflag, const float* g_ewo,
                                           float* g_ewq, float* g_ewk, float* g_ewv) {
  bool f32 = gflag[0] != 0.f;
  __shared__ float ew[CD];
  int which = blockIdx.x >> 3, h = blockIdx.x & 7, e = threadIdx.x;
  ew[e] = g_ewo[h * CD + e];
  __syncthreads();
  const void* W = which == 0 ? tWq : (which == 1 ? tWk : tWv);
  float a = 0;
  #pragma unroll 8
  for (int d = 0; d < CD; ++d) a += ew[d] * LD(W, d * CD + e, f32);
  (which == 0 ? g_ewq : (which == 1 ? g_ewk : g_ewv))[h * CD + e] = a;
}

// ---------------- K0c: per-TEM-head 8x8 score matrix C_h and value vector u_h ----------
__global__ __launch_bounds__(128) void k0c(const float* g_ewq, const float* g_ewk,
                                           const float* g_ewv, const float* g_wod,
                                           float* g_C, float* g_u) {
  int h = blockIdx.x, tid = threadIdx.x;
  if (tid < 64) {
    int a = tid >> 3, b2 = tid & 7;
    float c = 0;
    #pragma unroll
    for (int j = 0; j < CDH; ++j)
      c += g_ewq[a * CD + h * CDH + j] * g_ewk[b2 * CD + h * CDH + j];
    g_C[(h * 8 + a) * 8 + b2] = c;
  } else if (tid < 72) {
    int a = tid - 64;
    float c = 0;
    #pragma unroll
    for (int j = 0; j < CDH; ++j) c += g_ewv[a * CD + h * CDH + j] * g_wod[h * CDH + j];
    g_u[h * 8 + a] = c;
  }
}

// ---------------- K_ow: Ow[g,p] = sum_t out_w[t,p] * e^{+2pi i g t/512}, 1 block/g ------
__global__ __launch_bounds__(128) void k_ow(const void* out_w, const float* gflag,
                                            float* owr, float* owi) {
  bool f32 = gflag[0] != 0.f;
  __shared__ float twc[CT], tws[CT];
  int g = blockIdx.x, tid = threadIdx.x; // 128
  for (int t = tid; t < CT; t += 128) {
    int k = (g * t) & (CT - 1);
    float s, c;
    sincosf((float)k * (TWO_PI / CT), &s, &c);
    twc[t] = c; tws[t] = s;
  }
  __syncthreads();
  if (tid < CP) {
    float sr = 0, si = 0;
    #pragma unroll 8
    for (int t = 0; t < CT; ++t) {
      float w = LD(out_w, t * CP + tid, f32);
      sr += w * twc[t]; si += w * tws[t];
    }
    owr[g * CP + tid] = sr; owi[g * CP + tid] = si;
  }
}

// ---------------- K1: decomposition, coalesced 512x16 tiles --------------
__global__ __launch_bounds__(256) void k1_decomp(const void* x, const void* dec_w,
                                                 const void* dec_b, const float* gflag,
                                                 float* res, float* trend) {
  bool f32 = gflag[0] != 0.f;
  __shared__ float xl[CT][17]; // +1 pad
  int b = blockIdx.x >> 2, n0 = (blockIdx.x & 3) * 16;
  int tid = threadIdx.x; // 256
  size_t base = (size_t)b * CT * CN + n0;
  for (int i = tid; i < CT * 16; i += 256) {
    int t = i >> 4, j = i & 15;
    xl[t][j] = LD(x, base + (size_t)t * CN + j, f32);
  }
  __syncthreads();
  float w0 = LD(dec_w, 0, f32), w1 = LD(dec_w, 1, f32);
  float c0 = LD(dec_b, 0, f32), c1 = LD(dec_b, 1, f32);
  int j = tid & 15, tl = tid >> 4; // 16 t-lanes x 16 cols
  for (int k = 0; k < CT / 16; ++k) {
    int t = k * 16 + tl;
    float s17 = 0;
    #pragma unroll
    for (int o = -8; o <= 8; ++o) {
      int u = t + o; u = u < 0 ? 0 : (u > CT - 1 ? CT - 1 : u);
      s17 += xl[u][j];
    }
    float s49 = 0;
    #pragma unroll
    for (int o = -24; o <= 24; ++o) {
      int u = t + o; u = u < 0 ? 0 : (u > CT - 1 ? CT - 1 : u);
      s49 += xl[u][j];
    }
    float m0 = s17 * (1.f / 17.f), m1 = s49 * (1.f / 49.f);
    float xv = xl[t][j];
    float l0 = xv * w0 + c0, l1 = xv * w1 + c1;
    float mx = fmaxf(l0, l1);
    float e0 = __expf(l0 - mx), e1 = __expf(l1 - mx);
    float tr = (e0 * m0 + e1 * m1) / (e0 + e1);
    size_t o = ((size_t)(b * CT + t)) * CN + n0 + j;
    trend[o] = tr;
    res[o] = xv - tr;
  }
}

// ---------------- K2: trend MLP, 4 rows/block x 128 blocks, deep-ILP weight streaming ----
// Row activations are lane-uniform (LDS broadcast, free); the only memory stream is the
// coalesced weight read; 16 loads in flight per wave hides L2 latency.
template <bool F32>
__device__ __forceinline__ void k2_body(const float* __restrict__ trend, const void* w1,
                                        const void* bb1, const void* w2, const void* bb2,
                                        const void* w3, const void* bb3,
                                        float* __restrict__ trendo) {
  __shared__ float rows[4][CT];
  __shared__ float h1[4][CHID];
  __shared__ float h2[4][CHID];
  int r0 = blockIdx.x * 4; // 128 blocks
  int b = r0 >> 6, n0 = r0 & 63;
  int tid = threadIdx.x; // 256
  const float* tb = trend + (size_t)b * CT * CN + n0;
  for (int i = tid; i < 4 * CT; i += 256) {
    int q = i & 3, t = i >> 2;
    rows[q][t] = tb[(size_t)t * CN + q];
  }
  __syncthreads();
  int c = tid;
  float a0, a1, a2, a3;
  {
    float bias = LDT<F32>(bb1, c);
    a0 = a1 = a2 = a3 = 0.f;
    #pragma unroll 16
    for (int t = 0; t < CT; ++t) {
      float w = LDT<F32>(w1, t * CHID + c);
      a0 += rows[0][t] * w; a1 += rows[1][t] * w;
      a2 += rows[2][t] * w; a3 += rows[3][t] * w;
    }
    h1[0][c] = fmaxf(a0 + bias, 0.f); h1[1][c] = fmaxf(a1 + bias, 0.f);
    h1[2][c] = fmaxf(a2 + bias, 0.f); h1[3][c] = fmaxf(a3 + bias, 0.f);
  }
  __syncthreads();
  {
    float bias = LDT<F32>(bb2, c);
    a0 = a1 = a2 = a3 = 0.f;
    #pragma unroll 16
    for (int i = 0; i < CHID; ++i) {
      float w = LDT<F32>(w2, i * CHID + c);
      a0 += h1[0][i] * w; a1 += h1[1][i] * w;
      a2 += h1[2][i] * w; a3 += h1[3][i] * w;
    }
    h2[0][c] = fmaxf(a0 + bias, 0.f); h2[1][c] = fmaxf(a1 + bias, 0.f);
    h2[2][c] = fmaxf(a2 + bias, 0.f); h2[3][c] = fmaxf(a3 + bias, 0.f);
  }
  __syncthreads();
  if (tid < 2 * CP) {
    int p = tid < CP ? tid : tid - CP;
    int qh = tid < CP ? 0 : 2; // rows {0,1} or {2,3}
    float bias = LDT<F32>(bb3, p);
    a0 = a1 = 0.f;
    #pragma unroll 16
    for (int i = 0; i < CHID; ++i) {
      float w = LDT<F32>(w3, i * CP + p);
      a0 += h2[qh][i] * w; a1 += h2[qh + 1][i] * w;
    }
    trendo[((size_t)(b * CN + n0 + qh)) * CP + p] = a0 + bias;
    trendo[((size_t)(b * CN + n0 + qh + 1)) * CP + p] = a1 + bias;
  }
}

__global__ __launch_bounds__(256) void k2_mlp(const float* trend, const void* w1, const void* bb1,
                                              const void* w2, const void* bb2, const void* w3,
                                              const void* bb3, const float* gflag, float* trendo) {
  if (gflag[0] != 0.f)
    k2_body<true>(trend, w1, bb1, w2, bb2, w3, bb3, trendo);
  else
    k2_body<false>(trend, w1, bb1, w2, bb2, w3, bb3, trendo);
}

// ---------------- K3: CEM collapsed attention -> P[b,t,h,n] --------------
__global__ __launch_bounds__(64) void k3_cem(const float* res, const float* g_ch, float* P) {
  __shared__ float rowl[CN], twc[CN], tws[CN];
  __shared__ float Rr[CM], Ri[CM], aR[CM];
  __shared__ float Sr[CH * CM], Si[CH * CM], chl[CH];
  int blk = blockIdx.x;
  int b = blk >> 9, t = blk & 511;
  int tid = threadIdx.x; // 64
  rowl[tid] = res[((size_t)(b * CT + t)) * CN + tid];
  {
    float s, c;
    sincosf((float)tid * (TWO_PI / CN), &s, &c);
    twc[tid] = c; tws[tid] = s;
  }
  if (tid < CH) chl[tid] = g_ch[tid];
  __syncthreads();
  if (tid < CM) {
    float rr = 0, ri = 0;
    int idx = 0;
    for (int n2 = 0; n2 < CN; ++n2) {
      rr += rowl[n2] * twc[idx];
      ri -= rowl[n2] * tws[idx];
      idx = (idx + tid) & (CN - 1);
    }
    Rr[tid] = rr; Ri[tid] = ri; aR[tid] = sqrtf(rr * rr + ri * ri);
  }
  __syncthreads();
  float amax = 0;
  for (int m = 0; m < CM; ++m) amax = fmaxf(amax, aR[m]);
  for (int i = 0; i < 4; ++i) {
    int pair = tid + 64 * i;
    int h = pair >> 5, m = pair & 31;
    float alpha = 0.25f * chl[h] * aR[m];
    float den = 0, sr = 0, si = 0;
    for (int n2 = 0; n2 < CM; ++n2) {
      float e = __expf(alpha * (aR[n2] - amax));
      den += e; sr += e * Rr[n2]; si += e * Ri[n2];
    }
    Sr[pair] = sr / den; Si[pair] = si / den;
  }
  __syncthreads();
  float* Pb = P + ((size_t)(b * CT + t)) * CH * CN;
  int n2 = tid;
  for (int h = 0; h < CH; ++h) {
    float a = Sr[h * CM]; // f = 0 term (Re only; imag dropped per irfft semantics)
    int idx = n2 & (CN - 1);
    #pragma unroll
    for (int f = 1; f < CM; ++f) {
      a += 2.f * (Sr[h * CM + f] * twc[idx] - Si[h * CM + f] * tws[idx]);
      idx = (idx + n2) & (CN - 1);
    }
    Pb[h * CN + n2] = a * (1.f / CN);
  }
}

// ---------------- K4: Q[b,n,g,h] = sum_t P[b,t,h,n] e^{-2pi i g t / 512} --------------
// Twiddles via per-thread incremental complex rotation (no LDS in inner loop).
__global__ __launch_bounds__(256) void k4_qdft(const float* P, float* Q) {
  __shared__ float Pl[CT][CH];
  int blk = blockIdx.x;
  int b = blk >> 6, n = blk & 63;
  int tid = threadIdx.x; // 256
  for (int i = tid; i < CT * CH; i += 256) {
    int t = i >> 3, h = i & 7;
    Pl[t][h] = P[(((size_t)(b * CT + t)) * CH + h) * CN + n];
  }
  __syncthreads();
  int g1 = tid >> 3, h = tid & 7, g2 = g1 + 32;
  float s1, c1, s2, c2;
  sincosf((float)g1 * (TWO_PI / CT), &s1, &c1);
  sincosf((float)g2 * (TWO_PI / CT), &s2, &c2);
  float wr1 = 1.f, wi1 = 0.f, wr2 = 1.f, wi2 = 0.f;
  float r1 = 0, i1 = 0, r2 = 0, i2 = 0;
  #pragma unroll 8
  for (int t = 0; t < CT; ++t) {
    float p = Pl[t][h];
    r1 += p * wr1; i1 += p * wi1;
    r2 += p * wr2; i2 += p * wi2;
    // w *= e^{-2pi i g/512}: (wr + i wi)(c - i s)
    float nr1 = wr1 * c1 + wi1 * s1; wi1 = wi1 * c1 - wr1 * s1; wr1 = nr1;
    float nr2 = wr2 * c2 + wi2 * s2; wi2 = wi2 * c2 - wr2 * s2; wr2 = nr2;
  }
  float* Qb = Q + ((size_t)(b * CN + n)) * CG * CH * 2;
  Qb[(g1 * CH + h) * 2] = r1; Qb[(g1 * CH + h) * 2 + 1] = i1;
  Qb[(g2 * CH + h) * 2] = r2; Qb[(g2 * CH + h) * 2 + 1] = i2;
}

// ---------------- K5: rank-8 TEM attention, online softmax (no sv[] spill) --------
__global__ __launch_bounds__(512) void k5_tem(const float* Q, const float* g_C, const float* g_u,
                                              const float* owr, const float* owi,
                                              const float* trendo, const void* dr_b,
                                              const void* out_b, const void* wfuse,
                                              const float* gflag, void* out) {
  __shared__ float QL[CG][16];      // [g][a*2 + {re,im}]
  __shared__ float Cl[512];         // [h][a][b]
  __shared__ float Ul[CH][8];
  __shared__ float2 vdL[CH][CG];
  __shared__ float2 zL[CH][CG];
  __shared__ float zrow[CG][2];
  int blk = blockIdx.x;
  int b = blk >> 6, n = blk & 63;
  int tid = threadIdx.x; // 512
  const float* Qb = Q + ((size_t)(b * CN + n)) * CG * CH * 2;
  ((float2*)&QL[0][0])[tid] = ((const float2*)Qb)[tid];
  Cl[tid] = g_C[tid];
  if (tid < 64) ((float*)Ul)[tid] = g_u[tid];
  __syncthreads();
  int h = tid >> 6, m = tid & 63;
  const float4* q4 = (const float4*)QL[m];
  float4 x0 = q4[0], x1 = q4[1], x2 = q4[2], x3 = q4[3];
  float ar[8] = {x0.x, x0.z, x1.x, x1.z, x2.x, x2.z, x3.x, x3.z};
  float ai[8] = {x0.y, x0.w, x1.y, x1.w, x2.y, x2.w, x3.y, x3.w};
  // vd[h][m] = Q8[m] . u_h
  {
    float vr = 0, vi = 0;
    #pragma unroll
    for (int a = 0; a < 8; ++a) { float u = Ul[h][a]; vr += ar[a] * u; vi += ai[a] * u; }
    vdL[h][m] = make_float2(vr, vi);
  }
  // Qt = Q8[m] . C_h (real C)
  float qtr[8], qti[8];
  #pragma unroll
  for (int bb = 0; bb < 8; ++bb) {
    float sr = 0, si = 0;
    #pragma unroll
    for (int a = 0; a < 8; ++a) {
      float c = Cl[(h * 8 + a) * 8 + bb];
      sr += ar[a] * c; si += ai[a] * c;
    }
    qtr[bb] = sr; qti[bb] = si;
  }
  __syncthreads(); // vdL visible
  // fused scores + online softmax + z accumulation (zero register arrays over g)
  float mx = -1e30f, den = 0.f, zr = 0.f, zi = 0.f;
  #pragma unroll 4
  for (int g = 0; g < CG; ++g) {
    const float4* k4p = (const float4*)QL[g];
    float4 y0 = k4p[0], y1 = k4p[1], y2 = k4p[2], y3 = k4p[3];
    float sr = qtr[0] * y0.x + qti[0] * y0.y + qtr[1] * y0.z + qti[1] * y0.w
             + qtr[2] * y1.x + qti[2] * y1.y + qtr[3] * y1.z + qti[3] * y1.w
             + qtr[4] * y2.x + qti[4] * y2.y + qtr[5] * y2.z + qti[5] * y2.w
             + qtr[6] * y3.x + qti[6] * y3.y + qtr[7] * y3.z + qti[7] * y3.w;
    float si = qti[0] * y0.x - qtr[0] * y0.y + qti[1] * y0.z - qtr[1] * y0.w
             + qti[2] * y1.x - qtr[2] * y1.y + qti[3] * y1.z - qtr[3] * y1.w
             + qti[4] * y2.x - qtr[4] * y2.y + qti[5] * y2.z - qtr[5] * y2.w
             + qti[6] * y3.x - qtr[6] * y3.y + qti[7] * y3.z - qtr[7] * y3.w;
    float s = 0.25f * sqrtf(sr * sr + si * si);
    if (s > mx) {
      float f = __expf(mx - s);
      den *= f; zr *= f; zi *= f; mx = s;
    }
    float e = __expf(s - mx);
    float2 vd = vdL[h][g];
    den += e; zr += e * vd.x; zi += e * vd.y;
  }
  float rv = 1.f / den;
  zL[h][m] = make_float2(zr * rv, zi * rv);
  __syncthreads();
  if (tid < 128) {
    int g = tid >> 1, c = tid & 1;
    float a = 0;
    #pragma unroll
    for (int hh = 0; hh < CH; ++hh) a += c ? zL[hh][g].y : zL[hh][g].x;
    zrow[g][c] = a;
  }
  __syncthreads();
  if (tid < CP) {
    bool f32 = gflag[0] != 0.f;
    int p = tid;
    float acc = zrow[0][0] * owr[p] - zrow[0][1] * owi[p];
    #pragma unroll 8
    for (int g = 1; g < CG; ++g)
      acc += 2.f * (zrow[g][0] * owr[g * CP + p] - zrow[g][1] * owi[g * CP + p]);
    float xo = acc * (1.f / CT) + LD(dr_b, 0, f32) * owr[p] + LD(out_b, p, f32);
    float val = LD(wfuse, 0, f32) * xo + LD(wfuse, 1, f32) * trendo[((size_t)(b * CN + n)) * CP + p];
    size_t oidx = ((size_t)(b * CP + p)) * CN + n;
    if (f32) ((float*)out)[oidx] = val;
    else ((bf16*)out)[oidx] = __float2bfloat16(val);
  }
}

extern "C" void kernel_launch(void* const* d_in, const int* in_sizes, int n_in,
                              void* d_out, int out_size, void* d_ws, size_t ws_size,
                              hipStream_t stream) {
  const void* x = d_in[0];
  const void* emb = d_in[1];
  const void* dec_w = d_in[2];
  const void* dec_b = d_in[3];
  const void* mlp_w1 = d_in[4];
  const void* mlp_b1 = d_in[5];
  const void* mlp_w2 = d_in[6];
  const void* mlp_b2 = d_in[7];
  const void* mlp_w3 = d_in[8];
  const void* mlp_b3 = d_in[9];
  const void* cWq = d_in[10];
  const void* cWk = d_in[11];
  const void* cWv = d_in[12];
  const void* cWo = d_in[13];
  const void* tWq = d_in[14];
  const void* tWk = d_in[15];
  const void* tWv = d_in[16];
  const void* tWo = d_in[17];
  const void* drw = d_in[18];
  const void* drb = d_in[19];
  const void* out_w = d_in[20];
  const void* out_b = d_in[21];
  const void* wfuse = d_in[22];

  float* W = (float*)d_ws;
  float* res = W;    W += (size_t)CB * CT * CN;
  float* trend = W;  W += (size_t)CB * CT * CN;
  float* trendo = W; W += (size_t)CB * CN * CP;
  float* Pbuf = W;   W += (size_t)CB * CT * CH * CN;
  float* Qbuf = W;   W += (size_t)CB * CN * CG * CH * 2;
  float* ch = W;     W += 8;
  float* ewo = W;    W += CH * CD;
  float* ewq = W;    W += CH * CD;
  float* ewk = W;    W += CH * CD;
  float* ewv = W;    W += CH * CD;
  float* wod = W;    W += CD;
  float* owr = W;    W += CG * CP;
  float* owi = W;    W += CG * CP;
  float* gC = W;     W += 512;
  float* gU = W;     W += 64;
  float* gflag = W;  W += 64;

  k_detect<<<1, 256, 0, stream>>>((const unsigned int*)x, gflag);
  k0a<<<1, 512, 0, stream>>>(emb, cWq, cWk, cWv, cWo, tWo, drw, gflag, ch, ewo, wod);
  k0b<<<24, 128, 0, stream>>>(tWq, tWk, tWv, gflag, ewo, ewq, ewk, ewv);
  k0c<<<8, 128, 0, stream>>>(ewq, ewk, ewv, wod, gC, gU);
  k_ow<<<CG, 128, 0, stream>>>(out_w, gflag, owr, owi);
  k1_decomp<<<CB * 4, 256, 0, stream>>>(x, dec_w, dec_b, gflag, res, trend);
  k2_mlp<<<CB * CN / 4, 256, 0, stream>>>(trend, mlp_w1, mlp_b1, mlp_w2, mlp_b2, mlp_w3, mlp_b3,
                                          gflag, trendo);
  k3_cem<<<CB * CT, 64, 0, stream>>>(res, ch, Pbuf);
  k4_qdft<<<CB * CN, 256, 0, stream>>>(Pbuf, Qbuf);
  k5_tem<<<CB * CN, 512, 0, stream>>>(Qbuf, gC, gU, owr, owi, trendo, drb, out_b, wfuse,
                                      gflag, d_out);
}

// Round 6
// 226.324 us; speedup vs baseline: 3.4134x; 1.4669x over previous
//
#include <hip/hip_runtime.h>
#include <hip/hip_bf16.h>

typedef __hip_bfloat16 bf16;

constexpr int CB = 8;     // batch
constexpr int CT = 512;   // T
constexpr int CN = 64;    // N
constexpr int CD = 128;   // D
constexpr int CP = 96;    // PRED
constexpr int CH = 8;     // HEADS
constexpr int CDH = 16;   // head dim
constexpr int CHID = 256; // HID
constexpr int CM = 32;    // CEM freq tokens
constexpr int CG = 64;    // TEM freq tokens
constexpr float TWO_PI = 6.28318530717958647692f;

// dtype-agnostic load: f==true -> input is float32, else bf16
__device__ __forceinline__ float LD(const void* p, size_t i, bool f) {
  return f ? ((const float*)p)[i] : __bfloat162float(((const bf16*)p)[i]);
}
template <bool F32>
__device__ __forceinline__ float LDT(const void* p, size_t i) {
  return F32 ? ((const float*)p)[i] : __bfloat162float(((const bf16*)p)[i]);
}

// inline dtype detection: every wave reads x[0..63] words; fp32 data -> low halves are
// mantissa bits -> ~80% absurd bf16 exponents; bf16 data -> ~0. Uniform per wave.
__device__ __forceinline__ bool detect_f32(const void* x) {
  const unsigned int* xw = (const unsigned int*)x;
  unsigned int w = xw[threadIdx.x & 63];
  unsigned int e = (w >> 7) & 0xFF;
  unsigned long long m = __ballot(e >= 0x90 || e <= 0x60);
  return __popcll(m) > 3;
}

__device__ __forceinline__ float2 pkfma(float2 a, float2 b, float2 c) {
  return make_float2(fmaf(a.x, b.x, c.x), fmaf(a.y, b.y, c.y));
}

// =================== L1: k1_decomp [0,32) | k_ow [32,96) | k0a [96] ===================
__global__ __launch_bounds__(256) void kL1(const void* x, const void* dec_w, const void* dec_b,
                                           const void* out_w, const void* emb, const void* cWq,
                                           const void* cWk, const void* cWv, const void* cWo,
                                           const void* tWo, const void* drw,
                                           float* res, float* trend, float* owr, float* owi,
                                           float* g_ch, float* g_ewo, float* g_wod) {
  __shared__ float sm[CT * 17]; // 34.8 KB union
  bool f32 = detect_f32(x);
  int blk = blockIdx.x, tid = threadIdx.x;
  if (blk < 32) {
    // ---- k1: decomposition, coalesced 512x16 tiles ----
    float (*xl)[17] = (float (*)[17])sm;
    int b = blk >> 2, n0 = (blk & 3) * 16;
    size_t base = (size_t)b * CT * CN + n0;
    for (int i = tid; i < CT * 16; i += 256) {
      int t = i >> 4, j = i & 15;
      xl[t][j] = LD(x, base + (size_t)t * CN + j, f32);
    }
    __syncthreads();
    float w0 = LD(dec_w, 0, f32), w1 = LD(dec_w, 1, f32);
    float c0 = LD(dec_b, 0, f32), c1 = LD(dec_b, 1, f32);
    int j = tid & 15, tl = tid >> 4;
    for (int k = 0; k < CT / 16; ++k) {
      int t = k * 16 + tl;
      float s17 = 0;
      #pragma unroll
      for (int o = -8; o <= 8; ++o) {
        int u = t + o; u = u < 0 ? 0 : (u > CT - 1 ? CT - 1 : u);
        s17 += xl[u][j];
      }
      float s49 = 0;
      #pragma unroll
      for (int o = -24; o <= 24; ++o) {
        int u = t + o; u = u < 0 ? 0 : (u > CT - 1 ? CT - 1 : u);
        s49 += xl[u][j];
      }
      float m0 = s17 * (1.f / 17.f), m1 = s49 * (1.f / 49.f);
      float xv = xl[t][j];
      float l0 = xv * w0 + c0, l1 = xv * w1 + c1;
      float mx = fmaxf(l0, l1);
      float e0 = __expf(l0 - mx), e1 = __expf(l1 - mx);
      float tr = (e0 * m0 + e1 * m1) / (e0 + e1);
      size_t o = ((size_t)(b * CT + t)) * CN + n0 + j;
      trend[o] = tr;
      res[o] = xv - tr;
    }
  } else if (blk < 96) {
    // ---- k_ow: Ow[g,p] = sum_t out_w[t,p] e^{+2pi i g t/512} ----
    float* twc = sm; float* tws = sm + CT;
    int g = blk - 32;
    for (int t = tid; t < CT; t += 256) {
      int k = (g * t) & (CT - 1);
      float s, c;
      sincosf((float)k * (TWO_PI / CT), &s, &c);
      twc[t] = c; tws[t] = s;
    }
    __syncthreads();
    if (tid < CP) {
      float sr = 0, si = 0;
      #pragma unroll 8
      for (int t = 0; t < CT; ++t) {
        float w = LD(out_w, t * CP + tid, f32);
        sr += w * twc[t]; si += w * tws[t];
      }
      owr[g * CP + tid] = sr; owi[g * CP + tid] = si;
    }
  } else {
    // ---- k0a: emb projections, ch, wod, ewo ----
    float* eml = sm; float* drl = sm + 128; float* eql = sm + 256;
    float* ekl = sm + 384; float* evl = sm + 512;
    if (tid < 128) eml[tid] = LD(emb, tid, f32);
    else drl[tid - 128] = LD(drw, tid - 128, f32);
    __syncthreads();
    int e = tid & 127;
    for (int pass = 0; pass < 2; ++pass) {
      int grp = pass * 2 + (tid >> 7);
      if (grp < 3) {
        const void* W = grp == 0 ? cWq : (grp == 1 ? cWk : cWv);
        float a = 0;
        #pragma unroll 8
        for (int d = 0; d < CD; ++d) a += eml[d] * LD(W, d * CD + e, f32);
        (grp == 0 ? eql : (grp == 1 ? ekl : evl))[e] = a;
      } else {
        float a = 0;
        #pragma unroll 8
        for (int d = 0; d < CD; ++d) a += LD(tWo, e * CD + d, f32) * drl[d];
        g_wod[e] = a;
      }
    }
    __syncthreads();
    if (tid < CH) {
      float c = 0;
      for (int j = 0; j < CDH; ++j) c += eql[tid * CDH + j] * ekl[tid * CDH + j];
      g_ch[tid] = fabsf(c);
    }
    int half = tid >> 7;
    for (int hh = 0; hh < 4; ++hh) {
      int h = half * 4 + hh;
      float a = 0;
      #pragma unroll
      for (int j = 0; j < CDH; ++j) a += evl[h * CDH + j] * LD(cWo, (h * CDH + j) * CD + e, f32);
      g_ewo[h * CD + e] = a;
    }
  }
}

// =================== L2: k2 [0,128) | k3 [128,1152) | k0b [1152,1164) ===================
template <bool F32>
__device__ __forceinline__ void k2_body(float* sm, const float* __restrict__ trend, const void* w1,
                                        const void* bb1, const void* w2, const void* bb2,
                                        const void* w3, const void* bb3,
                                        float* __restrict__ trendo) {
  float* rows = sm;          // [4][512]
  float* h1 = sm + 2048;     // [4][256]
  float* h2 = sm + 3072;     // [4][256]
  int r0 = blockIdx.x * 4;
  int b = r0 >> 6, n0 = r0 & 63;
  int tid = threadIdx.x;
  const float* tb = trend + (size_t)b * CT * CN + n0;
  for (int i = tid; i < 4 * CT; i += 256) {
    int q = i & 3, t = i >> 2;
    rows[q * CT + t] = tb[(size_t)t * CN + q];
  }
  __syncthreads();
  int c = tid;
  float a0, a1, a2, a3;
  {
    float bias = LDT<F32>(bb1, c);
    a0 = a1 = a2 = a3 = 0.f;
    #pragma unroll 16
    for (int t = 0; t < CT; ++t) {
      float w = LDT<F32>(w1, t * CHID + c);
      a0 += rows[0 * CT + t] * w; a1 += rows[1 * CT + t] * w;
      a2 += rows[2 * CT + t] * w; a3 += rows[3 * CT + t] * w;
    }
    h1[0 * CHID + c] = fmaxf(a0 + bias, 0.f); h1[1 * CHID + c] = fmaxf(a1 + bias, 0.f);
    h1[2 * CHID + c] = fmaxf(a2 + bias, 0.f); h1[3 * CHID + c] = fmaxf(a3 + bias, 0.f);
  }
  __syncthreads();
  {
    float bias = LDT<F32>(bb2, c);
    a0 = a1 = a2 = a3 = 0.f;
    #pragma unroll 16
    for (int i = 0; i < CHID; ++i) {
      float w = LDT<F32>(w2, i * CHID + c);
      a0 += h1[0 * CHID + i] * w; a1 += h1[1 * CHID + i] * w;
      a2 += h1[2 * CHID + i] * w; a3 += h1[3 * CHID + i] * w;
    }
    h2[0 * CHID + c] = fmaxf(a0 + bias, 0.f); h2[1 * CHID + c] = fmaxf(a1 + bias, 0.f);
    h2[2 * CHID + c] = fmaxf(a2 + bias, 0.f); h2[3 * CHID + c] = fmaxf(a3 + bias, 0.f);
  }
  __syncthreads();
  if (tid < 2 * CP) {
    int p = tid < CP ? tid : tid - CP;
    int qh = tid < CP ? 0 : 2;
    float bias = LDT<F32>(bb3, p);
    a0 = a1 = 0.f;
    #pragma unroll 16
    for (int i = 0; i < CHID; ++i) {
      float w = LDT<F32>(w3, i * CP + p);
      a0 += h2[qh * CHID + i] * w; a1 += h2[(qh + 1) * CHID + i] * w;
    }
    trendo[((size_t)(b * CN + n0 + qh)) * CP + p] = a0 + bias;
    trendo[((size_t)(b * CN + n0 + qh + 1)) * CP + p] = a1 + bias;
  }
}

__global__ __launch_bounds__(256) void kL2(const void* x, const float* trend, const void* w1,
                                           const void* bb1, const void* w2, const void* bb2,
                                           const void* w3, const void* bb3, float* trendo,
                                           const float* res, const float* g_ch, float* P,
                                           const void* tWq, const void* tWk, const void* tWv,
                                           const float* g_ewo, float* g_ewq, float* g_ewk,
                                           float* g_ewv) {
  __shared__ float sm[4096]; // 16 KB union
  bool f32 = detect_f32(x);
  int blk = blockIdx.x, tid = threadIdx.x;
  if (blk < 128) {
    if (f32) k2_body<true>(sm, trend, w1, bb1, w2, bb2, w3, bb3, trendo);
    else     k2_body<false>(sm, trend, w1, bb1, w2, bb2, w3, bb3, trendo);
  } else if (blk < 1152) {
    // ---- k3: CEM collapsed attention, 4 t's per block (one per wave) ----
    float* rowl = sm;            // [4][64]
    float* twc = sm + 256;       // [64]
    float* tws = sm + 320;       // [64]
    float* chl = sm + 384;       // [8]
    float* Rr = sm + 392;        // [4][32]
    float* Ri = sm + 520;        // [4][32]
    float* aR = sm + 648;        // [4][32]
    float* Sr = sm + 776;        // [4][256]
    float* Si = sm + 1800;       // [4][256]
    int tblk = blk - 128;
    int b = tblk >> 7;
    int w = tid >> 6, lane = tid & 63;
    int t = ((tblk & 127) << 2) + w;
    rowl[w * 64 + lane] = res[((size_t)(b * CT + t)) * CN + lane];
    if (w == 0) {
      float s, c;
      sincosf((float)lane * (TWO_PI / CN), &s, &c);
      twc[lane] = c; tws[lane] = s;
    }
    if (tid < CH) chl[tid] = g_ch[tid];
    __syncthreads();
    if (lane < CM) {
      float rr = 0, ri = 0;
      int idx = 0;
      for (int n2 = 0; n2 < CN; ++n2) {
        rr += rowl[w * 64 + n2] * twc[idx];
        ri -= rowl[w * 64 + n2] * tws[idx];
        idx = (idx + lane) & (CN - 1);
      }
      Rr[w * 32 + lane] = rr; Ri[w * 32 + lane] = ri;
      aR[w * 32 + lane] = sqrtf(rr * rr + ri * ri);
    }
    __syncthreads();
    float amax = 0;
    for (int m = 0; m < CM; ++m) amax = fmaxf(amax, aR[w * 32 + m]);
    for (int i = 0; i < 4; ++i) {
      int pair = lane + 64 * i;
      int h = pair >> 5, m = pair & 31;
      float alpha = 0.25f * chl[h] * aR[w * 32 + m];
      float den = 0, sr = 0, si = 0;
      for (int n2 = 0; n2 < CM; ++n2) {
        float e = __expf(alpha * (aR[w * 32 + n2] - amax));
        den += e; sr += e * Rr[w * 32 + n2]; si += e * Ri[w * 32 + n2];
      }
      Sr[w * 256 + pair] = sr / den; Si[w * 256 + pair] = si / den;
    }
    __syncthreads();
    int n2 = lane;
    float av[8];
    for (int h = 0; h < CH; ++h) {
      float a = Sr[w * 256 + h * CM]; // f=0 term (Re only)
      int idx = n2 & (CN - 1);
      #pragma unroll
      for (int f = 1; f < CM; ++f) {
        a += 2.f * (Sr[w * 256 + h * CM + f] * twc[idx] - Si[w * 256 + h * CM + f] * tws[idx]);
        idx = (idx + n2) & (CN - 1);
      }
      av[h] = a * (1.f / CN);
    }
    // transposed layout P[b][n][t][h] -> coalesced k4 reads
    float* Pb = P + (((size_t)(b * CN + n2)) * CT + t) * CH;
    ((float4*)Pb)[0] = make_float4(av[0], av[1], av[2], av[3]);
    ((float4*)Pb)[1] = make_float4(av[4], av[5], av[6], av[7]);
  } else {
    // ---- k0b: ewq/ewk/ewv = ewo @ tW{q,k,v}, 2 (which,h) pairs per block ----
    float* ew = sm; // [2][128]
    int pairIdx = (blk - 1152) * 2 + (tid >> 7);
    int which = pairIdx >> 3, h = pairIdx & 7, e = tid & 127;
    ew[(tid >> 7) * 128 + e] = g_ewo[h * CD + e];
    __syncthreads();
    const void* W = which == 0 ? tWq : (which == 1 ? tWk : tWv);
    float a = 0;
    #pragma unroll 8
    for (int d = 0; d < CD; ++d) a += ew[(tid >> 7) * 128 + d] * LD(W, d * CD + e, f32);
    (which == 0 ? g_ewq : (which == 1 ? g_ewk : g_ewv))[h * CD + e] = a;
  }
}

// =================== L3: k4 [0,512) | k0c [512] ===================
__global__ __launch_bounds__(256) void kL3(const float* P, float* Q, const float* g_ewq,
                                           const float* g_ewk, const float* g_ewv,
                                           const float* g_wod, float* g_C, float* g_u) {
  __shared__ float sm[4096]; // 16 KB (k4 Pl)
  int blk = blockIdx.x, tid = threadIdx.x;
  if (blk < 512) {
    // ---- k4: Q[b,n,g,h] = sum_t P[b,n,t,h] e^{-2pi i g t/512}, coalesced load ----
    float* Pl = sm; // [512][8]
    int b = blk >> 6, n = blk & 63;
    const float4* Pp4 = (const float4*)(P + ((size_t)(b * CN + n)) * CT * CH);
    float4* Pl4 = (float4*)Pl;
    for (int i = tid; i < CT * CH / 4; i += 256) Pl4[i] = Pp4[i];
    __syncthreads();
    int g1 = tid >> 3, h = tid & 7, g2 = g1 + 32;
    float s1, c1, s2, c2;
    sincosf((float)g1 * (TWO_PI / CT), &s1, &c1);
    sincosf((float)g2 * (TWO_PI / CT), &s2, &c2);
    float wr1 = 1.f, wi1 = 0.f, wr2 = 1.f, wi2 = 0.f;
    float r1 = 0, i1 = 0, r2 = 0, i2 = 0;
    #pragma unroll 8
    for (int t = 0; t < CT; ++t) {
      float p = Pl[t * CH + h];
      r1 += p * wr1; i1 += p * wi1;
      r2 += p * wr2; i2 += p * wi2;
      float nr1 = wr1 * c1 + wi1 * s1; wi1 = wi1 * c1 - wr1 * s1; wr1 = nr1;
      float nr2 = wr2 * c2 + wi2 * s2; wi2 = wi2 * c2 - wr2 * s2; wr2 = nr2;
    }
    float* Qb = Q + ((size_t)(b * CN + n)) * CG * CH * 2;
    Qb[(g1 * CH + h) * 2] = r1; Qb[(g1 * CH + h) * 2 + 1] = i1;
    Qb[(g2 * CH + h) * 2] = r2; Qb[(g2 * CH + h) * 2 + 1] = i2;
  } else {
    // ---- k0c: all heads' C_h (8x8) and u_h ----
    for (int id = tid; id < 512 + 64; id += 256) {
      if (id < 512) {
        int h = id >> 6, a = (id >> 3) & 7, b2 = id & 7;
        float c = 0;
        #pragma unroll
        for (int j = 0; j < CDH; ++j)
          c += g_ewq[a * CD + h * CDH + j] * g_ewk[b2 * CD + h * CDH + j];
        g_C[id] = c;
      } else {
        int r = id - 512;
        int h = r >> 3, a = r & 7;
        float c = 0;
        #pragma unroll
        for (int j = 0; j < CDH; ++j) c += g_ewv[a * CD + h * CDH + j] * g_wod[h * CDH + j];
        g_u[r] = c;
      }
    }
  }
}

// =================== L4: k5 rank-8 TEM attention, pk-fma scores, online softmax ==========
__global__ __launch_bounds__(512) void k5_tem(const void* x, const float* Q, const float* g_C,
                                              const float* g_u, const float* owr,
                                              const float* owi, const float* trendo,
                                              const void* dr_b, const void* out_b,
                                              const void* wfuse, void* out) {
  __shared__ float QL[CG][16];      // [g][b*2 + {re,im}]
  __shared__ float Cl[512];         // [h][a][b]
  __shared__ float Ul[CH][8];
  __shared__ float2 vdL[CH][CG];
  __shared__ float2 zL[CH][CG];
  __shared__ float zrow[CG][2];
  bool f32 = detect_f32(x);
  int blk = blockIdx.x;
  int b = blk >> 6, n = blk & 63;
  int tid = threadIdx.x; // 512
  const float* Qb = Q + ((size_t)(b * CN + n)) * CG * CH * 2;
  ((float2*)&QL[0][0])[tid] = ((const float2*)Qb)[tid];
  Cl[tid] = g_C[tid];
  if (tid < 64) ((float*)Ul)[tid] = g_u[tid];
  __syncthreads();
  int h = tid >> 6, m = tid & 63;
  // own row (Qr,Qi) pairs
  float2 qp[8];
  {
    const float4* q4 = (const float4*)QL[m];
    #pragma unroll
    for (int j = 0; j < 4; ++j) {
      float4 y = q4[j];
      qp[2 * j] = make_float2(y.x, y.y);
      qp[2 * j + 1] = make_float2(y.z, y.w);
    }
  }
  // vd[h][m] = Q8[m] . u_h
  {
    float vr = 0, vi = 0;
    #pragma unroll
    for (int a = 0; a < 8; ++a) { float u = Ul[h][a]; vr += qp[a].x * u; vi += qp[a].y * u; }
    vdL[h][m] = make_float2(vr, vi);
  }
  // u[b]=(qtr,qti), v[b]=(qti,-qtr) where qt = Q8[m] . C_h
  float2 uu[8], vv[8];
  #pragma unroll
  for (int bb = 0; bb < 8; ++bb) {
    float sr = 0, si = 0;
    #pragma unroll
    for (int a = 0; a < 8; ++a) {
      float c = Cl[(h * 8 + a) * 8 + bb];
      sr += qp[a].x * c; si += qp[a].y * c;
    }
    uu[bb] = make_float2(sr, si);
    vv[bb] = make_float2(si, -sr);
  }
  __syncthreads(); // vdL visible
  // fused scores (packed-f32 dots) + online softmax + z accumulation
  float mx = -1e30f, den = 0.f, zr = 0.f, zi = 0.f;
  #pragma unroll 4
  for (int g = 0; g < CG; ++g) {
    const float4* k4p = (const float4*)QL[g];
    float2 sr2 = make_float2(0.f, 0.f), si2 = make_float2(0.f, 0.f);
    #pragma unroll
    for (int j = 0; j < 4; ++j) {
      float4 y = k4p[j];
      float2 y0 = make_float2(y.x, y.y), y1 = make_float2(y.z, y.w);
      sr2 = pkfma(uu[2 * j], y0, sr2); si2 = pkfma(vv[2 * j], y0, si2);
      sr2 = pkfma(uu[2 * j + 1], y1, sr2); si2 = pkfma(vv[2 * j + 1], y1, si2);
    }
    float sr = sr2.x + sr2.y;        // qtr.Qr + qti.Qi
    float si = si2.x + si2.y;        // qti.Qr - qtr.Qi
    float s = 0.25f * sqrtf(sr * sr + si * si);
    if (s > mx) {
      float f = __expf(mx - s);
      den *= f; zr *= f; zi *= f; mx = s;
    }
    float e = __expf(s - mx);
    float2 vd = vdL[h][g];
    den += e; zr += e * vd.x; zi += e * vd.y;
  }
  float rv = 1.f / den;
  zL[h][m] = make_float2(zr * rv, zi * rv);
  __syncthreads();
  if (tid < 128) {
    int g = tid >> 1, c = tid & 1;
    float a = 0;
    #pragma unroll
    for (int hh = 0; hh < CH; ++hh) a += c ? zL[hh][g].y : zL[hh][g].x;
    zrow[g][c] = a;
  }
  __syncthreads();
  if (tid < CP) {
    int p = tid;
    float acc = zrow[0][0] * owr[p] - zrow[0][1] * owi[p]; // g=0 (bin-0 imag dropped)
    #pragma unroll 8
    for (int g = 1; g < CG; ++g)
      acc += 2.f * (zrow[g][0] * owr[g * CP + p] - zrow[g][1] * owi[g * CP + p]);
    float xo = acc * (1.f / CT) + LD(dr_b, 0, f32) * owr[p] + LD(out_b, p, f32);
    float val = LD(wfuse, 0, f32) * xo + LD(wfuse, 1, f32) * trendo[((size_t)(b * CN + n)) * CP + p];
    size_t oidx = ((size_t)(b * CP + p)) * CN + n;
    if (f32) ((float*)out)[oidx] = val;
    else ((bf16*)out)[oidx] = __float2bfloat16(val);
  }
}

extern "C" void kernel_launch(void* const* d_in, const int* in_sizes, int n_in,
                              void* d_out, int out_size, void* d_ws, size_t ws_size,
                              hipStream_t stream) {
  const void* x = d_in[0];
  const void* emb = d_in[1];
  const void* dec_w = d_in[2];
  const void* dec_b = d_in[3];
  const void* mlp_w1 = d_in[4];
  const void* mlp_b1 = d_in[5];
  const void* mlp_w2 = d_in[6];
  const void* mlp_b2 = d_in[7];
  const void* mlp_w3 = d_in[8];
  const void* mlp_b3 = d_in[9];
  const void* cWq = d_in[10];
  const void* cWk = d_in[11];
  const void* cWv = d_in[12];
  const void* cWo = d_in[13];
  const void* tWq = d_in[14];
  const void* tWk = d_in[15];
  const void* tWv = d_in[16];
  const void* tWo = d_in[17];
  const void* drw = d_in[18];
  const void* drb = d_in[19];
  const void* out_w = d_in[20];
  const void* out_b = d_in[21];
  const void* wfuse = d_in[22];

  float* W = (float*)d_ws;
  float* res = W;    W += (size_t)CB * CT * CN;
  float* trend = W;  W += (size_t)CB * CT * CN;
  float* trendo = W; W += (size_t)CB * CN * CP;
  float* Pbuf = W;   W += (size_t)CB * CT * CH * CN;
  float* Qbuf = W;   W += (size_t)CB * CN * CG * CH * 2;
  float* ch = W;     W += 8;
  float* ewo = W;    W += CH * CD;
  float* ewq = W;    W += CH * CD;
  float* ewk = W;    W += CH * CD;
  float* ewv = W;    W += CH * CD;
  float* wod = W;    W += CD;
  float* owr = W;    W += CG * CP;
  float* owi = W;    W += CG * CP;
  float* gC = W;     W += 512;
  float* gU = W;     W += 64;

  kL1<<<97, 256, 0, stream>>>(x, dec_w, dec_b, out_w, emb, cWq, cWk, cWv, cWo, tWo, drw,
                              res, trend, owr, owi, ch, ewo, wod);
  kL2<<<1164, 256, 0, stream>>>(x, trend, mlp_w1, mlp_b1, mlp_w2, mlp_b2, mlp_w3, mlp_b3,
                                trendo, res, ch, Pbuf, tWq, tWk, tWv, ewo, ewq, ewk, ewv);
  kL3<<<513, 256, 0, stream>>>(Pbuf, Qbuf, ewq, ewk, ewv, wod, gC, gU);
  k5_tem<<<CB * CN, 512, 0, stream>>>(x, Qbuf, gC, gU, owr, owi, trendo, drb, out_b, wfuse,
                                      d_out);
}